// Round 12
// baseline (2381.755 us; speedup 1.0000x reference)
//
#include <hip/hip_runtime.h>
#include <hip/hip_bf16.h>
#include <math.h>

typedef __hip_bfloat16 bf16;
typedef __bf16 bf16x8 __attribute__((ext_vector_type(8)));
typedef float f32x4 __attribute__((ext_vector_type(4)));

__device__ __forceinline__ f32x4 zero4() { f32x4 z; z[0]=0.f; z[1]=0.f; z[2]=0.f; z[3]=0.f; return z; }

__device__ __forceinline__ void gload_lds16(const void* g, void* l) {
  __builtin_amdgcn_global_load_lds(
      (const __attribute__((address_space(1))) void*)g,
      (__attribute__((address_space(3))) void*)l, 16, 0, 0);
}

__device__ __forceinline__ float gelu_f(float t) {
  return 0.5f*t*(1.0f+erff(t*0.70710678118654752f));
}

// 2D XCD supertile over the (x,y) grid (z excluded).
template<int SW>
__device__ __forceinline__ void xcd_tile(int& bx, int& by) {
  const int gx = gridDim.x;
  const int nwg = gx * gridDim.y;
  const int orig = blockIdx.y * gx + blockIdx.x;
  const int L = nwg >> 3;
  const int c = orig & 7, i = orig >> 3;
  const int gxW = gx / SW;
  const int H = L / SW;
  bx = (c % gxW) * SW + i % SW;
  by = (c / gxW) * H + i / SW;
}

// ---------------- GEMM v9: m201 8-phase template. 256x256, BK=64, 8 waves ----------------
// 2 K-tiles per iteration (buf0=even, buf1=odd); 1 half-tile staged per phase;
// vmcnt(6) only at phases 4 and 8; two barriers per phase.
// C(MxN) = A(MxK,bf16) * B^T (B is NxK bf16). K2 = this dispatch's K-slice extent,
// Kstride = full row stride (elements). blockIdx.z selects K-slice [z*K2,(z+1)*K2).
// MODE 1: outb=acc(bf16); 3: outb=gelu(acc+bias); 5: split->outf+z*M*N (z0 adds bias); 6: split->outf+z*M*N
template<int MODE, int SW>
__global__ __launch_bounds__(512, 2) void k_gemm2(
    const bf16* __restrict__ A, const bf16* __restrict__ B,
    int M, int N, int K2, int Kstride,
    float* __restrict__ outf, bf16* __restrict__ outb,
    const float* __restrict__ bias)
{
  // buf: [0,16K) A-lo | [16K,32K) A-hi | [32K,48K) B-lo | [48K,64K) B-hi
  __shared__ __align__(16) char lds[2][65536];
  const int t = threadIdx.x;
  const int w = t>>6, l = t&63;
  const int wr = w>>2, wc = w&3;
  const int lr = l&15, l4 = l>>4, l7 = l&7;

  int bx, by; xcd_tile<SW>(bx, by);
  const int m0 = by*256, n0 = bx*256;

  const int NT = K2 >> 6;                 // even for all shapes used
  const int NJ = NT >> 1;
  const size_t rs = (size_t)Kstride*2;
  const size_t zoff = (size_t)blockIdx.z * K2 * 2;
  const char* gA = (const char*)A + (size_t)m0*rs + zoff;
  const char* gB = (const char*)B + (size_t)n0*rs + zoff;

  // which: 0=A-lo, 1=A-hi, 2=B-lo, 3=B-hi ; 2 gloads per thread (one 128x64 half)
  auto stageHalf = [&](char* bufp, int which, int T){
    const char* gbase = (which < 2) ? gA : gB;
    const int rowbase = (which & 1) << 7;
    const size_t kb = (size_t)T*128;
    #pragma unroll
    for (int i=0;i<2;i++){
      const int row = rowbase + i*64 + (t>>3);
      gload_lds16(gbase + (size_t)row*rs + kb + (size_t)(((t&7) ^ (row&7))<<4),
                  bufp + which*16384 + i*8192 + t*16);
    }
  };

  f32x4 acc[2][2][4][2];
  #pragma unroll
  for (int a=0;a<2;a++)
    #pragma unroll
    for (int b=0;b<2;b++)
      #pragma unroll
      for (int c=0;c<4;c++)
        #pragma unroll
        for (int d=0;d<2;d++) acc[a][b][c][d] = zero4();

  bf16x8 aCur[4][2], bCur[2][2];
  auto readA = [&](const char* Ab, int mhalf){
    #pragma unroll
    for (int mi=0;mi<4;mi++){
      const int ar = mhalf*128 + wr*64 + mi*16 + lr;
      #pragma unroll
      for (int ks=0;ks<2;ks++)
        aCur[mi][ks] = *reinterpret_cast<const bf16x8*>(Ab + ar*128 + (((ks*4+l4) ^ l7)<<4));
    }
  };
  auto readB = [&](const char* Bb, int nhalf){
    #pragma unroll
    for (int ni=0;ni<2;ni++){
      const int br = nhalf*128 + wc*32 + ni*16 + lr;
      #pragma unroll
      for (int ks=0;ks<2;ks++)
        bCur[ni][ks] = *reinterpret_cast<const bf16x8*>(Bb + 32768 + br*128 + (((ks*4+l4) ^ l7)<<4));
    }
  };

  #define BARPRE  do { asm volatile("" ::: "memory"); __builtin_amdgcn_s_barrier(); } while(0)
  #define BARPOST do { asm volatile("" ::: "memory"); __builtin_amdgcn_s_barrier(); } while(0)
  #define QMFMA(MH,NH)                                                              \
    __builtin_amdgcn_s_setprio(1);                                                  \
    _Pragma("unroll")                                                               \
    for (int mi=0;mi<4;mi++)                                                        \
      _Pragma("unroll")                                                             \
      for (int ni=0;ni<2;ni++)                                                      \
        _Pragma("unroll")                                                           \
        for (int ks=0;ks<2;ks++)                                                    \
          acc[MH][NH][mi][ni] = __builtin_amdgcn_mfma_f32_16x16x32_bf16(            \
              aCur[mi][ks], bCur[ni][ks], acc[MH][NH][mi][ni], 0,0,0);              \
    __builtin_amdgcn_s_setprio(0);

  char* b0 = &lds[0][0];
  char* b1 = &lds[1][0];

  // prologue: buf0 = tile 0 (all 4 halves first in FIFO), buf1 = tile 1 (3 halves);
  // vmcnt(6) retires exactly buf0's 4 halves.
  stageHalf(b0, 0, 0); stageHalf(b0, 3, 0); stageHalf(b0, 1, 0); stageHalf(b0, 2, 0);
  stageHalf(b1, 0, 1); stageHalf(b1, 3, 1); stageHalf(b1, 1, 1);
  asm volatile("s_waitcnt vmcnt(6)" ::: "memory");
  __builtin_amdgcn_s_barrier();

  for (int j=0; j<NJ; ++j) {
    const int t0 = 2*j, t1 = 2*j+1;
    const bool more = (j+1 < NJ);

    // ph1: (0,0) on t0 ; stage b1.Blo(t1)  [old b1.Blo last read prev ph8]
    readA(b0,0); readB(b0,0);
    stageHalf(b1, 2, t1);
    BARPRE; QMFMA(0,0); BARPOST;

    // ph2: (0,1) ; stage b0.Alo(t0+2)
    readB(b0,1);
    if (more) stageHalf(b0, 0, t0+2);
    BARPRE; QMFMA(0,1); BARPOST;

    // ph3: (1,1) ; stage b0.Bhi(t0+2)
    readA(b0,1);
    if (more) stageHalf(b0, 3, t0+2);
    BARPRE; QMFMA(1,1); BARPOST;

    // ph4: (1,0) ; stage b0.Ahi(t0+2) ; counted wait -> buf1 (tile t1) fully landed
    readB(b0,0);
    if (more) { stageHalf(b0, 1, t0+2); asm volatile("s_waitcnt vmcnt(6)" ::: "memory"); }
    else      {                         asm volatile("s_waitcnt vmcnt(0)" ::: "memory"); }
    BARPRE; QMFMA(1,0); BARPOST;

    // ph5: (0,0) on t1 ; stage b0.Blo(t0+2)
    readA(b1,0); readB(b1,0);
    if (more) stageHalf(b0, 2, t0+2);
    BARPRE; QMFMA(0,0); BARPOST;

    // ph6: (0,1) ; stage b1.Alo(t1+2)
    readB(b1,1);
    if (more) stageHalf(b1, 0, t1+2);
    BARPRE; QMFMA(0,1); BARPOST;

    // ph7: (1,1) ; stage b1.Bhi(t1+2)
    readA(b1,1);
    if (more) stageHalf(b1, 3, t1+2);
    BARPRE; QMFMA(1,1); BARPOST;

    // ph8: (1,0) ; stage b1.Ahi(t1+2) ; counted wait -> buf0 (tile t0+2) fully landed
    readB(b1,0);
    if (more) { stageHalf(b1, 1, t1+2); asm volatile("s_waitcnt vmcnt(6)" ::: "memory"); }
    BARPRE; QMFMA(1,0); BARPOST;
  }
  #undef QMFMA
  #undef BARPRE
  #undef BARPOST

  const int rbase = m0 + wr*64 + l4*4;
  const int cbase = n0 + wc*32 + lr;
  float* po = (MODE>=5) ? outf + (size_t)blockIdx.z * M * N : outf;
  #pragma unroll
  for (int mh=0;mh<2;mh++)
    #pragma unroll
    for (int nh=0;nh<2;nh++)
      #pragma unroll
      for (int mi=0;mi<4;mi++)
        #pragma unroll
        for (int ni=0;ni<2;ni++) {
          const int col = cbase + nh*128 + ni*16;
          #pragma unroll
          for (int q=0;q<4;q++) {
            const int row = rbase + mh*128 + mi*16 + q;
            const size_t idx = (size_t)row*N + col;
            float v = acc[mh][nh][mi][ni][q];
            if (MODE==1)      outb[idx] = __float2bfloat16(v);
            else if (MODE==3) outb[idx] = __float2bfloat16(gelu_f(v + bias[col]));
            else if (MODE==5) po[idx] = (blockIdx.z==0) ? v + bias[col] : v;
            else if (MODE==6) po[idx] = v;
          }
        }
}

// ---------------- transpose: 64x64 tiles, float4 reads, ushort4 writes ----------------
__global__ __launch_bounds__(256) void k_tr64(const float* __restrict__ in, bf16* __restrict__ out,
                                              int K, int N)
{
  __shared__ float tile[64][65];
  const int n0 = blockIdx.x*64, k0 = blockIdx.y*64;
  const int t = threadIdx.x;
  const int tr = t>>4;
  const int tc = (t&15)*4;
  #pragma unroll
  for (int i=0;i<4;i++) {
    const int k = tr + i*16;
    float4 v = *reinterpret_cast<const float4*>(&in[(size_t)(k0+k)*N + n0 + tc]);
    tile[k][tc+0]=v.x; tile[k][tc+1]=v.y; tile[k][tc+2]=v.z; tile[k][tc+3]=v.w;
  }
  __syncthreads();
  #pragma unroll
  for (int i=0;i<4;i++) {
    const int n = tr + i*16;
    bf16 r[4];
    #pragma unroll
    for (int c=0;c<4;c++) r[c] = __float2bfloat16(tile[tc+c][n]);
    *reinterpret_cast<ushort4*>(&out[(size_t)(n0+n)*K + k0 + tc]) = *reinterpret_cast<const ushort4*>(r);
  }
}

__global__ void k_cvt(const float* __restrict__ in, bf16* __restrict__ out, int n4) {
  int i = blockIdx.x*256 + threadIdx.x;
  if (i < n4) {
    float4 v = reinterpret_cast<const float4*>(in)[i];
    out[i*4+0]=__float2bfloat16(v.x); out[i*4+1]=__float2bfloat16(v.y);
    out[i*4+2]=__float2bfloat16(v.z); out[i*4+3]=__float2bfloat16(v.w);
  }
}

__global__ void k_cossin(float* __restrict__ c, float* __restrict__ s) {
  int idx = blockIdx.x*256 + threadIdx.x;   // 1024*64
  int j = idx & 63, pos = idx >> 6;
  float inv = powf(10000.f, -(float)(2*j)/128.f);
  float a = (float)pos * inv;
  c[idx] = cosf(a); s[idx] = sinf(a);
}

// rope (vectorized): lane j2 handles out dims {2*j2, 2*j2+1} of one (row,head)
__global__ void k_rope(const bf16* __restrict__ in, int instride, bf16* __restrict__ out,
                       const float* __restrict__ cosc, const float* __restrict__ sinc) {
  int idx = blockIdx.x*256 + threadIdx.x;   // 4096*16*32
  int j2 = idx & 31, h = (idx>>5) & 15, row = idx >> 9;
  int s = row & 1023;
  const bf16* rp = in + (size_t)row*instride + h*128 + j2*4;
  union { ushort4 u; bf16 b[4]; } vv;
  vv.u = *reinterpret_cast<const ushort4*>(rp);
  float a0 = __bfloat162float(vv.b[0]), b0 = __bfloat162float(vv.b[1]);
  float a1 = __bfloat162float(vv.b[2]), b1 = __bfloat162float(vv.b[3]);
  const int d = 2*j2;
  float c0 = cosc[s*64+d], s0 = sinc[s*64+d];
  float c1 = cosc[s*64+d+1], s1 = sinc[s*64+d+1];
  bf16* op = out + (size_t)row*2048 + h*128;
  union { ushort2 u; bf16 b[2]; } r0, r1;
  r0.b[0] = __float2bfloat16(a0*c0 - b0*s0);
  r0.b[1] = __float2bfloat16(a1*c1 - b1*s1);
  r1.b[0] = __float2bfloat16(a0*s0 + b0*c0);
  r1.b[1] = __float2bfloat16(a1*s1 + b1*c1);
  *reinterpret_cast<ushort2*>(op + d)      = r0.u;
  *reinterpret_cast<ushort2*>(op + 64 + d) = r1.u;
}

// V (row=b*1024+s of [4096 x instride], col=h*128+d) -> Vt[(bh*128+d)*1024 + s]
__global__ __launch_bounds__(256) void k_vtrans(const bf16* __restrict__ vlin, int instride,
                                                bf16* __restrict__ vt) {
  __shared__ bf16 tile[32][33];
  const int bh = blockIdx.x, s0 = blockIdx.y*32, d0 = blockIdx.z*32;
  const int b = bh>>4, h = bh&15;
  const int tx = threadIdx.x & 31, ty = threadIdx.x >> 5;
  #pragma unroll
  for (int i=ty;i<32;i+=8)
    tile[i][tx] = vlin[((size_t)(b*1024 + s0+i))*instride + h*128 + d0 + tx];
  __syncthreads();
  #pragma unroll
  for (int i=ty;i<32;i+=8)
    vt[((size_t)(bh*128 + d0+i))*1024 + s0 + tx] = tile[tx][i];
}

// ---------------- flash attention: LDS-staged K/V, double-buffered, XOR-swizzled ----------------
__global__ __launch_bounds__(256) void k_attn(const bf16* __restrict__ Q, const bf16* __restrict__ Kr,
                                              const bf16* __restrict__ Vt, bf16* __restrict__ O)
{
  __shared__ __align__(16) bf16 Kl[2][64*128];
  __shared__ __align__(16) bf16 Vl[2][128*64];
  __shared__ __align__(16) bf16 plds[4][16*64];
  const int t = threadIdx.x, w = t>>6, l = t&63;
  const int bh = blockIdx.x, b = bh>>4, h = bh&15;
  const int q0 = blockIdx.y*64 + w*16;
  const int l4 = l>>4, lc = l&15;

  bf16x8 qf[4];
  const bf16* qbase = Q + ((size_t)(b*1024 + q0 + lc))*2048 + h*128 + l4*8;
  #pragma unroll
  for (int kk=0;kk<4;kk++) qf[kk] = *reinterpret_cast<const bf16x8*>(qbase + kk*32);

  const char* Kg = (const char*)(Kr + ((size_t)(b*1024))*2048 + h*128);
  const char* Vg = (const char*)(Vt + ((size_t)(bh*128))*1024);

  auto stageK = [&](int buf, int kv0) {
    #pragma unroll
    for (int i=0;i<4;i++) {
      const int X = (i*256 + t)*16;
      const int row = X >> 8, colb = X & 255;
      gload_lds16(Kg + (size_t)(kv0+row)*4096 + (colb ^ ((row&7)<<4)), (char*)&Kl[buf][0] + X);
    }
  };
  auto stageV = [&](int buf, int kv0) {
    #pragma unroll
    for (int i=0;i<4;i++) {
      const int X = (i*256 + t)*16;
      const int row = X >> 7, colb = X & 127;
      gload_lds16(Vg + (size_t)row*2048 + kv0*2 + (colb ^ ((row&7)<<4)), (char*)&Vl[buf][0] + X);
    }
  };

  f32x4 oacc[8];
  #pragma unroll
  for (int n=0;n<8;n++) oacc[n]=zero4();
  float mrow[4], lrow[4];
  #pragma unroll
  for (int j=0;j<4;j++){ mrow[j]=-1e30f; lrow[j]=0.f; }
  const float scale = 0.08838834764831845f;

  stageK(0,0); stageV(0,0);
  __syncthreads();
  int cur = 0;

  for (int it=0; it<16; ++it) {
    const int kv0 = it*64;
    if (it < 15) { stageK(cur^1, kv0+64); stageV(cur^1, kv0+64); }

    f32x4 sc[4];
    #pragma unroll
    for (int c=0;c<4;c++) sc[c]=zero4();
    __builtin_amdgcn_s_setprio(1);
    #pragma unroll
    for (int c=0;c<4;c++) {
      const int krow = c*16+lc;
      const char* kp = (const char*)&Kl[cur][0] + krow*256;
      #pragma unroll
      for (int kk=0;kk<4;kk++) {
        bf16x8 kf = *reinterpret_cast<const bf16x8*>(kp + ((kk*64 + l4*16) ^ ((krow&7)<<4)));
        sc[c] = __builtin_amdgcn_mfma_f32_16x16x32_bf16(qf[kk], kf, sc[c], 0,0,0);
      }
    }
    __builtin_amdgcn_s_setprio(0);

    float alpha[4];
    #pragma unroll
    for (int j=0;j<4;j++) {
      float v0=sc[0][j]*scale, v1=sc[1][j]*scale, v2=sc[2][j]*scale, v3=sc[3][j]*scale;
      float mx = fmaxf(fmaxf(v0,v1),fmaxf(v2,v3));
      #pragma unroll
      for (int d=1;d<16;d<<=1) mx = fmaxf(mx, __shfl_xor(mx,d));
      float mn = fmaxf(mrow[j], mx);
      alpha[j] = __expf(mrow[j]-mn);
      mrow[j] = mn;
      float p0=__expf(v0-mn), p1=__expf(v1-mn), p2=__expf(v2-mn), p3=__expf(v3-mn);
      sc[0][j]=p0; sc[1][j]=p1; sc[2][j]=p2; sc[3][j]=p3;
      float ps = (p0+p1)+(p2+p3);
      #pragma unroll
      for (int d=1;d<16;d<<=1) ps += __shfl_xor(ps,d);
      lrow[j] = lrow[j]*alpha[j] + ps;
    }
    #pragma unroll
    for (int n=0;n<8;n++)
      #pragma unroll
      for (int j=0;j<4;j++) oacc[n][j]*=alpha[j];

    char* pw = (char*)&plds[w][0];
    #pragma unroll
    for (int c=0;c<4;c++)
      #pragma unroll
      for (int j=0;j<4;j++) {
        const int qrow = l4*4+j;
        *reinterpret_cast<bf16*>(pw + qrow*128 + ((c*32 + lc*2) ^ ((qrow&7)<<4))) =
            __float2bfloat16(sc[c][j]);
      }
    bf16x8 pf[2];
    #pragma unroll
    for (int ks=0;ks<2;ks++)
      pf[ks] = *reinterpret_cast<const bf16x8*>(pw + lc*128 + ((ks*64 + l4*16) ^ ((lc&7)<<4)));

    __builtin_amdgcn_s_setprio(1);
    #pragma unroll
    for (int n=0;n<8;n++) {
      const int drow = n*16+lc;
      const char* vp = (const char*)&Vl[cur][0] + drow*128;
      #pragma unroll
      for (int ks=0;ks<2;ks++) {
        bf16x8 vf = *reinterpret_cast<const bf16x8*>(vp + ((ks*64 + l4*16) ^ ((drow&7)<<4)));
        oacc[n] = __builtin_amdgcn_mfma_f32_16x16x32_bf16(pf[ks], vf, oacc[n], 0,0,0);
      }
    }
    __builtin_amdgcn_s_setprio(0);

    __syncthreads();
    cur ^= 1;
  }

  #pragma unroll
  for (int n=0;n<8;n++)
    #pragma unroll
    for (int j=0;j<4;j++) {
      float v = oacc[n][j]/lrow[j];
      O[((size_t)(b*1024 + q0 + l4*4 + j))*2048 + h*128 + n*16 + lc] = __float2bfloat16(v);
    }
}

// ---------------- LayerNorm (vectorized): over 2048 cols of (in0 [+in1] [+in2] [+addv(b)]) ----
__global__ __launch_bounds__(256) void k_ln(const float* __restrict__ in0, const float* __restrict__ in1,
                                            const float* __restrict__ in2, const float* __restrict__ addv,
                                            float* __restrict__ outsum,
                                            float* __restrict__ outf, bf16* __restrict__ outb,
                                            const float* __restrict__ g, const float* __restrict__ bta)
{
  const int row = blockIdx.x;
  const int b = row >> 10;
  const size_t base = (size_t)row*2048;
  const int c0 = threadIdx.x * 8;
  f32x4 v0 = *(const f32x4*)(in0 + base + c0);
  f32x4 v1 = *(const f32x4*)(in0 + base + c0 + 4);
  if (in1) { v0 += *(const f32x4*)(in1 + base + c0); v1 += *(const f32x4*)(in1 + base + c0 + 4); }
  if (in2) { v0 += *(const f32x4*)(in2 + base + c0); v1 += *(const f32x4*)(in2 + base + c0 + 4); }
  if (addv){ v0 += *(const f32x4*)(addv + b*2048 + c0); v1 += *(const f32x4*)(addv + b*2048 + c0 + 4); }
  if (outsum) { *(f32x4*)(outsum + base + c0) = v0; *(f32x4*)(outsum + base + c0 + 4) = v1; }
  float s = (v0[0]+v0[1])+(v0[2]+v0[3]) + (v1[0]+v1[1])+(v1[2]+v1[3]);
  __shared__ float red[256];
  red[threadIdx.x]=s; __syncthreads();
  for (int o=128;o>0;o>>=1){ if(threadIdx.x<o) red[threadIdx.x]+=red[threadIdx.x+o]; __syncthreads(); }
  float mean = red[0] * (1.f/2048.f);
  __syncthreads();
  float vs=0.f;
  #pragma unroll
  for (int i=0;i<4;i++){ float d=v0[i]-mean; vs+=d*d; }
  #pragma unroll
  for (int i=0;i<4;i++){ float d=v1[i]-mean; vs+=d*d; }
  red[threadIdx.x]=vs; __syncthreads();
  for (int o=128;o>0;o>>=1){ if(threadIdx.x<o) red[threadIdx.x]+=red[threadIdx.x+o]; __syncthreads(); }
  float inv = rsqrtf(red[0]*(1.f/2048.f) + 1e-5f);
  f32x4 g0 = *(const f32x4*)(g + c0),  g1v = *(const f32x4*)(g + c0 + 4);
  f32x4 b0 = *(const f32x4*)(bta + c0), b1v = *(const f32x4*)(bta + c0 + 4);
  f32x4 r0, r1;
  #pragma unroll
  for (int i=0;i<4;i++) r0[i] = (v0[i]-mean)*inv*g0[i] + b0[i];
  #pragma unroll
  for (int i=0;i<4;i++) r1[i] = (v1[i]-mean)*inv*g1v[i] + b1v[i];
  if (outf) { *(f32x4*)(outf + base + c0) = r0; *(f32x4*)(outf + base + c0 + 4) = r1; }
  if (outb) {
    union { ushort u[8]; uint4 v; } ob;
    #pragma unroll
    for (int i=0;i<4;i++) { ob.u[i] = __bfloat16_as_ushort(__float2bfloat16(r0[i]));
                            ob.u[4+i] = __bfloat16_as_ushort(__float2bfloat16(r1[i])); }
    *reinterpret_cast<uint4*>(outb + base + c0) = ob.v;
  }
}

// ---------------- pool: two-stage, vectorized ----------------
__global__ __launch_bounds__(256) void k_poolp(const float* __restrict__ in0, const float* __restrict__ in1,
                                               const float* __restrict__ in2, float* __restrict__ part) {
  const int ch = blockIdx.x, b = blockIdx.y;
  const int t = threadIdx.x;
  f32x4 a0 = zero4(), a1 = zero4();
  #pragma unroll 4
  for (int r=0;r<16;++r) {
    const size_t base = ((size_t)(b*1024 + ch*16 + r))*2048;
    a0 += *(const f32x4*)(in0 + base + t*4);
    a1 += *(const f32x4*)(in0 + base + 1024 + t*4);
    if (in1) { a0 += *(const f32x4*)(in1 + base + t*4); a1 += *(const f32x4*)(in1 + base + 1024 + t*4); }
    if (in2) { a0 += *(const f32x4*)(in2 + base + t*4); a1 += *(const f32x4*)(in2 + base + 1024 + t*4); }
  }
  float* pp = part + ((size_t)(ch*4 + b))*2048;
  *(f32x4*)(pp + t*4) = a0;
  *(f32x4*)(pp + 1024 + t*4) = a1;
}

__global__ __launch_bounds__(256) void k_pools(const float* __restrict__ part, float* __restrict__ out) {
  const int b = blockIdx.y;
  const int c = blockIdx.x*1024 + threadIdx.x*4;
  f32x4 s = zero4();
  #pragma unroll 8
  for (int ch=0;ch<64;++ch)
    s += *(const f32x4*)(part + ((size_t)(ch*4+b))*2048 + c);
  #pragma unroll
  for (int i=0;i<4;i++) s[i] *= (1.f/1024.f);
  *(f32x4*)(out + b*2048 + c) = s;
}

__global__ __launch_bounds__(256) void k_gate(const float* __restrict__ xp, const float* __restrict__ wg,
                                              const float* __restrict__ bg, const float* __restrict__ tau,
                                              float* __restrict__ hf)
{
  const int n = blockIdx.x*256 + threadIdx.x;
  const int b = blockIdx.y;
  float s = bg[n];
  const float* xr = xp + b*2048;
  for (int k=0;k<2048;k++) s += xr[k]*wg[(size_t)k*2048 + n];
  float gate = 1.f/(1.f+__expf(-s));
  float tf = 0.1f + 9.9f/(1.f+__expf(-tau[n]));
  hf[b*2048+n] = 0.1f*gate*xr[n]/tf;
}

// ---------------- head ----------------
__global__ void k_qm(const float* __restrict__ pooled, const float* __restrict__ w_mp,
                     const float* __restrict__ b_mp, float* __restrict__ qm) {
  int n = blockIdx.x*256 + threadIdx.x;  // 512
  int b = blockIdx.y;
  float s = b_mp[n];
  for (int k=0;k<2048;k++) s += pooled[b*2048+k]*w_mp[(size_t)k*512+n];
  qm[b*512+n]=s;
}

__global__ void k_mscore(const float* __restrict__ qm, const float* __restrict__ bank,
                         float* __restrict__ mattn) {
  int n = blockIdx.x*256 + threadIdx.x;
  if (n >= 10000) return;
  const float sc = 0.04419417382415922f;  // 1/sqrt(512)
  #pragma unroll
  for (int b=0;b<4;b++){
    float s=0.f;
    for (int k=0;k<512;k++) s += qm[b*512+k]*bank[(size_t)n*512+k];
    mattn[b*10000+n] = s*sc;
  }
}

__global__ __launch_bounds__(256) void k_msoftmax(float* __restrict__ mattn) {
  int b = blockIdx.x;
  __shared__ float red[256];
  float mx=-1e30f;
  for (int i=threadIdx.x;i<10000;i+=256) mx=fmaxf(mx, mattn[b*10000+i]);
  red[threadIdx.x]=mx; __syncthreads();
  for (int o=128;o>0;o>>=1){ if(threadIdx.x<o) red[threadIdx.x]=fmaxf(red[threadIdx.x],red[threadIdx.x+o]); __syncthreads(); }
  mx=red[0]; __syncthreads();
  float sm=0.f;
  for (int i=threadIdx.x;i<10000;i+=256){ float e=__expf(mattn[b*10000+i]-mx); mattn[b*10000+i]=e; sm+=e; }
  red[threadIdx.x]=sm; __syncthreads();
  for (int o=128;o>0;o>>=1){ if(threadIdx.x<o) red[threadIdx.x]+=red[threadIdx.x+o]; __syncthreads(); }
  float inv = 1.f/red[0];
  for (int i=threadIdx.x;i<10000;i+=256) mattn[b*10000+i]*=inv;
}

__global__ void k_memmid(const float* __restrict__ mattn, const float* __restrict__ bank,
                         float* __restrict__ part) {
  int d = blockIdx.x*256 + threadIdx.x;  // 512
  int b = blockIdx.y, ch = blockIdx.z;   // 16 chunks x 625
  float s=0.f;
  for (int n=ch*625;n<(ch+1)*625;n++) s += mattn[b*10000+n]*bank[(size_t)n*512+d];
  part[(size_t)ch*2048 + b*512 + d]=s;
}

__global__ void k_midsum(const float* __restrict__ part, float* __restrict__ mid) {
  int i = blockIdx.x*256 + threadIdx.x;  // 2048
  float s=0.f;
  #pragma unroll
  for (int ch=0;ch<16;ch++) s += part[(size_t)ch*2048 + i];
  mid[i]=s;
}

__global__ void k_feat(const float* __restrict__ mid, const float* __restrict__ w_mr,
                       const float* __restrict__ b_mr, const float* __restrict__ pooled,
                       float* __restrict__ feat) {
  int n = blockIdx.x*256 + threadIdx.x;  // 2048
  int b = blockIdx.y;
  float s = b_mr[n];
  for (int d=0;d<512;d++) s += mid[b*512+d]*w_mr[(size_t)d*2048+n];
  feat[b*2048+n] = pooled[b*2048+n] + s;
}

__global__ void k_mlp1(const float* __restrict__ feat, const float* __restrict__ w,
                       const float* __restrict__ bias, float* __restrict__ out) {
  int n = blockIdx.x*256 + threadIdx.x;  // 1024
  int b = blockIdx.y;
  float s = bias[n];
  for (int k=0;k<2048;k++) s += feat[b*2048+k]*w[(size_t)k*1024+n];
  out[b*1024+n] = gelu_f(s);
}

__global__ void k_out(const float* __restrict__ a1, const float* __restrict__ w_a2, const float* __restrict__ b_a2,
                      const float* __restrict__ v1, const float* __restrict__ w_v2, const float* __restrict__ b_v2,
                      float* __restrict__ out) {
  int idx = blockIdx.x*256 + threadIdx.x;  // 1024
  if (idx < 1024) {
    int b = idx>>8, n = idx&255;
    float s = b_a2[n];
    for (int k=0;k<1024;k++) s += a1[b*1024+k]*w_a2[(size_t)k*256+n];
    out[b*256+n]=s;
  }
  if (idx < 4) {
    float s = b_v2[0];
    for (int k=0;k<1024;k++) s += v1[idx*1024+k]*w_v2[k];
    out[1024+idx]=s;
  }
}

extern "C" void kernel_launch(void* const* d_in, const int* in_sizes, int n_in,
                              void* d_out, int out_size, void* d_ws, size_t ws_size,
                              hipStream_t stream)
{
  (void)in_sizes; (void)n_in; (void)out_size;
  const float* x     = (const float*)d_in[0];
  const float* w_in  = (const float*)d_in[1];
  const float* b_in  = (const float*)d_in[2];
  const float* g_in  = (const float*)d_in[3];
  const float* be_in = (const float*)d_in[4];
  const float* wq    = (const float*)d_in[5];
  const float* wk    = (const float*)d_in[6];
  const float* wv    = (const float*)d_in[7];
  const float* wo    = (const float*)d_in[8];
  const float* g1    = (const float*)d_in[11];
  const float* be1   = (const float*)d_in[12];
  const float* g2    = (const float*)d_in[13];
  const float* be2   = (const float*)d_in[14];
  const float* wff1  = (const float*)d_in[15];
  const float* bff1  = (const float*)d_in[16];
  const float* wff2  = (const float*)d_in[17];
  const float* bff2  = (const float*)d_in[18];
  const float* wgate = (const float*)d_in[19];
  const float* bgate = (const float*)d_in[20];
  const float* tauff = (const float*)d_in[21];
  const float* bank  = (const float*)d_in[22];
  const float* w_mp  = (const float*)d_in[23];
  const float* b_mp  = (const float*)d_in[24];
  const float* w_mr  = (const float*)d_in[25];
  const float* b_mr  = (const float*)d_in[26];
  const float* w_a1  = (const float*)d_in[27];
  const float* b_a1  = (const float*)d_in[28];
  const float* w_a2  = (const float*)d_in[29];
  const float* b_a2  = (const float*)d_in[30];
  const float* w_v1  = (const float*)d_in[31];
  const float* b_v1  = (const float*)d_in[32];
  const float* w_v2  = (const float*)d_in[33];
  const float* b_v2  = (const float*)d_in[34];
  float* out = (float*)d_out;

  char* ws = (char*)d_ws;
  size_t o = 0;
  auto alloc = [&](size_t bytes)->char* { char* p = ws + o; o += (bytes + 255) & ~(size_t)255; return p; };
  bf16*  WINT   = (bf16*) alloc(2048ull*1024*2);
  bf16*  WT     = (bf16*) alloc(33554432ull);
  float* XF     = (float*)alloc(33554432ull);
  bf16*  XBF    = (bf16*) alloc(16777216ull);
  float* COS    = (float*)alloc(262144);
  float* SIN    = (float*)alloc(262144);
  float* XP     = (float*)alloc(32768);
  float* HF     = (float*)alloc(32768);
  float* POOLED = (float*)alloc(32768);
  float* QM     = (float*)alloc(8192);
  float* MATTN  = (float*)alloc(160000);
  float* MPART  = (float*)alloc(131072);
  float* MIDS   = (float*)alloc(8192);
  float* FEAT   = (float*)alloc(32768);
  float* A1     = (float*)alloc(16384);
  float* V1     = (float*)alloc(16384);
  float* PPART  = (float*)alloc(2097152);
  bf16*  BUF    = (bf16*) alloc(5ull*16777216);
  float* P0     = (float*)alloc(33554432ull);   // split-K partial 0 (4096x2048 fp32)
  float* P1     = (float*)alloc(33554432ull);   // split-K partial 1
  if (o > ws_size) return;

  const size_t EB = 8388608;
  bf16* QKV = BUF + 0*EB;          // fused q|k|v output, 4096 x 6144, spans BUF0..BUF2
  bf16* QR  = BUF + 3*EB;
  bf16* KR  = BUF + 4*EB;
  bf16* VT  = (bf16*)WT;           // into dead WTq/WTk (after QKV gemm)
  bf16* AO  = BUF + 0*EB;          // reuses QKV after ropes/vtrans
  bf16* MID = BUF + 0*EB;          // ff1 out, spans BUF0..BUF3
  bf16* XINB = BUF + 0*EB;

  bf16* WTq = WT;            bf16* WTk = WT + 4194304;
  bf16* WTv = WT + 8388608;  bf16* WTo = WT + 12582912;

  // ---- prologue ----
  k_cossin<<<256, 256, 0, stream>>>(COS, SIN);
  k_cvt<<<4096, 256, 0, stream>>>(x, XINB, 1048576);
  k_tr64<<<dim3(32,16), 256, 0, stream>>>(w_in, WINT, 1024, 2048);
  k_gemm2<5,4><<<dim3(8,16,2), 512, 0, stream>>>(XINB, WINT, 4096, 2048, 512, 1024, P0, (bf16*)nullptr, b_in);
  k_ln<<<4096, 256, 0, stream>>>(P0, P1, (const float*)nullptr, (const float*)nullptr,
                                 (float*)nullptr, XF, XBF, g_in, be_in);

  for (int i=0;i<2;i++) {
    const size_t ws2 = (size_t)i*2048*2048;
    k_tr64<<<dim3(32,32), 256, 0, stream>>>(wq + ws2, WTq, 2048, 2048);
    k_tr64<<<dim3(32,32), 256, 0, stream>>>(wk + ws2, WTk, 2048, 2048);
    k_tr64<<<dim3(32,32), 256, 0, stream>>>(wv + ws2, WTv, 2048, 2048);
    k_tr64<<<dim3(32,32), 256, 0, stream>>>(wo + ws2, WTo, 2048, 2048);
    // fused QKV projection: N=6144
    k_gemm2<1,6><<<dim3(24,16), 512, 0, stream>>>(XBF, WTq, 4096, 6144, 2048, 2048, (float*)nullptr, QKV, (const float*)nullptr);
    // RoPE + V transpose (VT lives in dead WTq/WTk region)
    k_rope<<<8192, 256, 0, stream>>>(QKV,        6144, QR, COS, SIN);
    k_rope<<<8192, 256, 0, stream>>>(QKV + 2048, 6144, KR, COS, SIN);
    k_vtrans<<<dim3(64,32,4), 256, 0, stream>>>(QKV + 4096, 6144, VT);
    // attention
    k_attn<<<dim3(64,16), 256, 0, stream>>>(QR, KR, VT, AO);
    // output proj, split-K=2 -> P0,P1 ; ln combines x1 = XF+P0+P1, writes back + bf16
    k_gemm2<6,4><<<dim3(8,16,2), 512, 0, stream>>>(AO, WTo, 4096, 2048, 1024, 2048, P0, (bf16*)nullptr, (const float*)nullptr);
    k_ln<<<4096, 256, 0, stream>>>(XF, P0, P1, (const float*)nullptr,
                                   XF, (float*)nullptr, XBF, g1 + i*2048, be1 + i*2048);
    // FFN
    k_tr64<<<dim3(128,32), 256, 0, stream>>>(wff1 + (size_t)i*2048*8192, WT, 2048, 8192);
    k_gemm2<3,8><<<dim3(32,16), 512, 0, stream>>>(XBF, WT, 4096, 8192, 2048, 2048, (float*)nullptr, MID, bff1 + i*8192);
    k_tr64<<<dim3(32,128), 256, 0, stream>>>(wff2 + (size_t)i*8192*2048, WT, 8192, 2048);
    // ff2, split-K=2 (K=8192 -> 2x4096) -> P0 (with bias), P1
    k_gemm2<5,4><<<dim3(8,16,2), 512, 0, stream>>>(MID, WT, 4096, 2048, 4096, 8192, P0, (bf16*)nullptr, bff2 + i*2048);
    // liquid gate + final LN (x2 = XF + P0 + P1)
    k_poolp<<<dim3(64,4), 256, 0, stream>>>(XF, P0, P1, PPART);
    k_pools<<<dim3(2,4), 256, 0, stream>>>(PPART, XP);
    k_gate<<<dim3(8,4), 256, 0, stream>>>(XP, wgate + ws2, bgate + i*2048, tauff + i*2048, HF);
    k_ln<<<4096, 256, 0, stream>>>(XF, P0, P1, HF,
                                   (float*)nullptr, XF, XBF, g2 + i*2048, be2 + i*2048);
  }

  // ---- head ----
  k_poolp<<<dim3(64,4), 256, 0, stream>>>(XF, (const float*)nullptr, (const float*)nullptr, PPART);
  k_pools<<<dim3(2,4), 256, 0, stream>>>(PPART, POOLED);
  k_qm<<<dim3(2,4), 256, 0, stream>>>(POOLED, w_mp, b_mp, QM);
  k_mscore<<<40, 256, 0, stream>>>(QM, bank, MATTN);
  k_msoftmax<<<4, 256, 0, stream>>>(MATTN);
  k_memmid<<<dim3(2,4,16), 256, 0, stream>>>(MATTN, bank, MPART);
  k_midsum<<<8, 256, 0, stream>>>(MPART, MIDS);
  k_feat<<<dim3(8,4), 256, 0, stream>>>(MIDS, w_mr, b_mr, POOLED, FEAT);
  k_mlp1<<<dim3(4,4), 256, 0, stream>>>(FEAT, w_a1, b_a1, A1);
  k_mlp1<<<dim3(4,4), 256, 0, stream>>>(FEAT, w_v1, b_v1, V1);
  k_out<<<4, 256, 0, stream>>>(A1, w_a2, b_a2, V1, w_v2, b_v2, out);
}

// Round 13
// 2364.330 us; speedup vs baseline: 1.0074x; 1.0074x over previous
//
#include <hip/hip_runtime.h>
#include <hip/hip_bf16.h>
#include <math.h>

typedef __hip_bfloat16 bf16;
typedef __bf16 bf16x8 __attribute__((ext_vector_type(8)));
typedef float f32x4 __attribute__((ext_vector_type(4)));

__device__ __forceinline__ f32x4 zero4() { f32x4 z; z[0]=0.f; z[1]=0.f; z[2]=0.f; z[3]=0.f; return z; }

__device__ __forceinline__ void gload_lds16(const void* g, void* l) {
  __builtin_amdgcn_global_load_lds(
      (const __attribute__((address_space(1))) void*)g,
      (__attribute__((address_space(3))) void*)l, 16, 0, 0);
}

__device__ __forceinline__ float gelu_f(float t) {
  return 0.5f*t*(1.0f+erff(t*0.70710678118654752f));
}

// 2D XCD supertile over the (x,y) grid (z excluded).
template<int SW>
__device__ __forceinline__ void xcd_tile(int& bx, int& by) {
  const int gx = gridDim.x;
  const int nwg = gx * gridDim.y;
  const int orig = blockIdx.y * gx + blockIdx.x;
  const int L = nwg >> 3;
  const int c = orig & 7, i = orig >> 3;
  const int gxW = gx / SW;
  const int H = L / SW;
  bx = (c % gxW) * SW + i % SW;
  by = (c / gxW) * H + i / SW;
}

// ---------------- GEMM v9: m201 8-phase template. 256x256, BK=64, 8 waves ----------------
// 2 K-tiles per iteration (buf0=even, buf1=odd); 1 half-tile staged per phase;
// vmcnt(6) only at phases 4 and 8; two barriers per phase.
// C(MxN) = A(MxK,bf16) * B^T (B is NxK bf16). K2 = this dispatch's K-slice extent,
// Kstride = full row stride (elements). blockIdx.z selects K-slice [z*K2,(z+1)*K2).
// MODE 1: outb=acc(bf16); 3: outb=gelu(acc+bias); 5: split->outf+z*M*N (z0 adds bias); 6: split->outf+z*M*N
template<int MODE, int SW>
__global__ __launch_bounds__(512, 2) void k_gemm2(
    const bf16* __restrict__ A, const bf16* __restrict__ B,
    int M, int N, int K2, int Kstride,
    float* __restrict__ outf, bf16* __restrict__ outb,
    const float* __restrict__ bias)
{
  // buf: [0,16K) A-lo | [16K,32K) A-hi | [32K,48K) B-lo | [48K,64K) B-hi
  __shared__ __align__(16) char lds[2][65536];
  const int t = threadIdx.x;
  const int w = t>>6, l = t&63;
  const int wr = w>>2, wc = w&3;
  const int lr = l&15, l4 = l>>4, l7 = l&7;

  int bx, by; xcd_tile<SW>(bx, by);
  const int m0 = by*256, n0 = bx*256;

  const int NT = K2 >> 6;                 // even for all shapes used
  const int NJ = NT >> 1;
  const size_t rs = (size_t)Kstride*2;
  const size_t zoff = (size_t)blockIdx.z * K2 * 2;
  const char* gA = (const char*)A + (size_t)m0*rs + zoff;
  const char* gB = (const char*)B + (size_t)n0*rs + zoff;

  // which: 0=A-lo, 1=A-hi, 2=B-lo, 3=B-hi ; 2 gloads per thread (one 128x64 half)
  auto stageHalf = [&](char* bufp, int which, int T){
    const char* gbase = (which < 2) ? gA : gB;
    const int rowbase = (which & 1) << 7;
    const size_t kb = (size_t)T*128;
    #pragma unroll
    for (int i=0;i<2;i++){
      const int row = rowbase + i*64 + (t>>3);
      gload_lds16(gbase + (size_t)row*rs + kb + (size_t)(((t&7) ^ (row&7))<<4),
                  bufp + which*16384 + i*8192 + t*16);
    }
  };

  f32x4 acc[2][2][4][2];
  #pragma unroll
  for (int a=0;a<2;a++)
    #pragma unroll
    for (int b=0;b<2;b++)
      #pragma unroll
      for (int c=0;c<4;c++)
        #pragma unroll
        for (int d=0;d<2;d++) acc[a][b][c][d] = zero4();

  bf16x8 aCur[4][2], bCur[2][2];
  auto readA = [&](const char* Ab, int mhalf){
    #pragma unroll
    for (int mi=0;mi<4;mi++){
      const int ar = mhalf*128 + wr*64 + mi*16 + lr;
      #pragma unroll
      for (int ks=0;ks<2;ks++)
        aCur[mi][ks] = *reinterpret_cast<const bf16x8*>(Ab + ar*128 + (((ks*4+l4) ^ l7)<<4));
    }
  };
  auto readB = [&](const char* Bb, int nhalf){
    #pragma unroll
    for (int ni=0;ni<2;ni++){
      const int br = nhalf*128 + wc*32 + ni*16 + lr;
      #pragma unroll
      for (int ks=0;ks<2;ks++)
        bCur[ni][ks] = *reinterpret_cast<const bf16x8*>(Bb + 32768 + br*128 + (((ks*4+l4) ^ l7)<<4));
    }
  };

  #define BARPRE  do { asm volatile("" ::: "memory"); __builtin_amdgcn_s_barrier(); } while(0)
  #define BARPOST do { asm volatile("" ::: "memory"); __builtin_amdgcn_s_barrier(); } while(0)
  #define QMFMA(MH,NH)                                                              \
    __builtin_amdgcn_s_setprio(1);                                                  \
    _Pragma("unroll")                                                               \
    for (int mi=0;mi<4;mi++)                                                        \
      _Pragma("unroll")                                                             \
      for (int ni=0;ni<2;ni++)                                                      \
        _Pragma("unroll")                                                           \
        for (int ks=0;ks<2;ks++)                                                    \
          acc[MH][NH][mi][ni] = __builtin_amdgcn_mfma_f32_16x16x32_bf16(            \
              aCur[mi][ks], bCur[ni][ks], acc[MH][NH][mi][ni], 0,0,0);              \
    __builtin_amdgcn_s_setprio(0);

  char* b0 = &lds[0][0];
  char* b1 = &lds[1][0];

  // prologue: buf0 = tile 0 (all 4 halves first in FIFO), buf1 = tile 1 (3 halves);
  // vmcnt(6) retires exactly buf0's 4 halves.
  stageHalf(b0, 0, 0); stageHalf(b0, 3, 0); stageHalf(b0, 1, 0); stageHalf(b0, 2, 0);
  stageHalf(b1, 0, 1); stageHalf(b1, 3, 1); stageHalf(b1, 1, 1);
  asm volatile("s_waitcnt vmcnt(6)" ::: "memory");
  __builtin_amdgcn_s_barrier();

  for (int j=0; j<NJ; ++j) {
    const int t0 = 2*j, t1 = 2*j+1;
    const bool more = (j+1 < NJ);

    // ph1: (0,0) on t0 ; stage b1.Blo(t1)  [old b1.Blo last read prev ph8]
    readA(b0,0); readB(b0,0);
    stageHalf(b1, 2, t1);
    BARPRE; QMFMA(0,0); BARPOST;

    // ph2: (0,1) ; stage b0.Alo(t0+2)
    readB(b0,1);
    if (more) stageHalf(b0, 0, t0+2);
    BARPRE; QMFMA(0,1); BARPOST;

    // ph3: (1,1) ; stage b0.Bhi(t0+2)
    readA(b0,1);
    if (more) stageHalf(b0, 3, t0+2);
    BARPRE; QMFMA(1,1); BARPOST;

    // ph4: (1,0) ; stage b0.Ahi(t0+2) ; counted wait -> buf1 (tile t1) fully landed
    readB(b0,0);
    if (more) { stageHalf(b0, 1, t0+2); asm volatile("s_waitcnt vmcnt(6)" ::: "memory"); }
    else      {                         asm volatile("s_waitcnt vmcnt(0)" ::: "memory"); }
    BARPRE; QMFMA(1,0); BARPOST;

    // ph5: (0,0) on t1 ; stage b0.Blo(t0+2)
    readA(b1,0); readB(b1,0);
    if (more) stageHalf(b0, 2, t0+2);
    BARPRE; QMFMA(0,0); BARPOST;

    // ph6: (0,1) ; stage b1.Alo(t1+2)
    readB(b1,1);
    if (more) stageHalf(b1, 0, t1+2);
    BARPRE; QMFMA(0,1); BARPOST;

    // ph7: (1,1) ; stage b1.Bhi(t1+2)
    readA(b1,1);
    if (more) stageHalf(b1, 3, t1+2);
    BARPRE; QMFMA(1,1); BARPOST;

    // ph8: (1,0) ; stage b1.Ahi(t1+2) ; counted wait -> buf0 (tile t0+2) fully landed
    readB(b1,0);
    if (more) { stageHalf(b1, 1, t1+2); asm volatile("s_waitcnt vmcnt(6)" ::: "memory"); }
    BARPRE; QMFMA(1,0); BARPOST;
  }
  #undef QMFMA
  #undef BARPRE
  #undef BARPOST

  const int rbase = m0 + wr*64 + l4*4;
  const int cbase = n0 + wc*32 + lr;
  float* po = (MODE>=5) ? outf + (size_t)blockIdx.z * M * N : outf;
  #pragma unroll
  for (int mh=0;mh<2;mh++)
    #pragma unroll
    for (int nh=0;nh<2;nh++)
      #pragma unroll
      for (int mi=0;mi<4;mi++)
        #pragma unroll
        for (int ni=0;ni<2;ni++) {
          const int col = cbase + nh*128 + ni*16;
          #pragma unroll
          for (int q=0;q<4;q++) {
            const int row = rbase + mh*128 + mi*16 + q;
            const size_t idx = (size_t)row*N + col;
            float v = acc[mh][nh][mi][ni][q];
            if (MODE==1)      outb[idx] = __float2bfloat16(v);
            else if (MODE==3) outb[idx] = __float2bfloat16(gelu_f(v + bias[col]));
            else if (MODE==5) po[idx] = (blockIdx.z==0) ? v + bias[col] : v;
            else if (MODE==6) po[idx] = v;
          }
        }
}

// ---------------- transpose: 64x64 tiles, float4 reads, ushort4 writes ----------------
__global__ __launch_bounds__(256) void k_tr64(const float* __restrict__ in, bf16* __restrict__ out,
                                              int K, int N)
{
  __shared__ float tile[64][65];
  const int n0 = blockIdx.x*64, k0 = blockIdx.y*64;
  const int t = threadIdx.x;
  const int tr = t>>4;
  const int tc = (t&15)*4;
  #pragma unroll
  for (int i=0;i<4;i++) {
    const int k = tr + i*16;
    float4 v = *reinterpret_cast<const float4*>(&in[(size_t)(k0+k)*N + n0 + tc]);
    tile[k][tc+0]=v.x; tile[k][tc+1]=v.y; tile[k][tc+2]=v.z; tile[k][tc+3]=v.w;
  }
  __syncthreads();
  #pragma unroll
  for (int i=0;i<4;i++) {
    const int n = tr + i*16;
    bf16 r[4];
    #pragma unroll
    for (int c=0;c<4;c++) r[c] = __float2bfloat16(tile[tc+c][n]);
    *reinterpret_cast<ushort4*>(&out[(size_t)(n0+n)*K + k0 + tc]) = *reinterpret_cast<const ushort4*>(r);
  }
}

__global__ void k_cvt(const float* __restrict__ in, bf16* __restrict__ out, int n4) {
  int i = blockIdx.x*256 + threadIdx.x;
  if (i < n4) {
    float4 v = reinterpret_cast<const float4*>(in)[i];
    out[i*4+0]=__float2bfloat16(v.x); out[i*4+1]=__float2bfloat16(v.y);
    out[i*4+2]=__float2bfloat16(v.z); out[i*4+3]=__float2bfloat16(v.w);
  }
}

__global__ void k_cossin(float* __restrict__ c, float* __restrict__ s) {
  int idx = blockIdx.x*256 + threadIdx.x;   // 1024*64
  int j = idx & 63, pos = idx >> 6;
  float inv = powf(10000.f, -(float)(2*j)/128.f);
  float a = (float)pos * inv;
  c[idx] = cosf(a); s[idx] = sinf(a);
}

// rope (vectorized): lane j2 handles out dims {2*j2, 2*j2+1} of one (row,head)
__global__ void k_rope(const bf16* __restrict__ in, int instride, bf16* __restrict__ out,
                       const float* __restrict__ cosc, const float* __restrict__ sinc) {
  int idx = blockIdx.x*256 + threadIdx.x;   // 4096*16*32
  int j2 = idx & 31, h = (idx>>5) & 15, row = idx >> 9;
  int s = row & 1023;
  const bf16* rp = in + (size_t)row*instride + h*128 + j2*4;
  union { ushort4 u; bf16 b[4]; } vv;
  vv.u = *reinterpret_cast<const ushort4*>(rp);
  float a0 = __bfloat162float(vv.b[0]), b0 = __bfloat162float(vv.b[1]);
  float a1 = __bfloat162float(vv.b[2]), b1 = __bfloat162float(vv.b[3]);
  const int d = 2*j2;
  float c0 = cosc[s*64+d], s0 = sinc[s*64+d];
  float c1 = cosc[s*64+d+1], s1 = sinc[s*64+d+1];
  bf16* op = out + (size_t)row*2048 + h*128;
  union { ushort2 u; bf16 b[2]; } r0, r1;
  r0.b[0] = __float2bfloat16(a0*c0 - b0*s0);
  r0.b[1] = __float2bfloat16(a1*c1 - b1*s1);
  r1.b[0] = __float2bfloat16(a0*s0 + b0*c0);
  r1.b[1] = __float2bfloat16(a1*s1 + b1*c1);
  *reinterpret_cast<ushort2*>(op + d)      = r0.u;
  *reinterpret_cast<ushort2*>(op + 64 + d) = r1.u;
}

// V (row=b*1024+s of [4096 x instride], col=h*128+d) -> Vt[(bh*128+d)*1024 + s]
__global__ __launch_bounds__(256) void k_vtrans(const bf16* __restrict__ vlin, int instride,
                                                bf16* __restrict__ vt) {
  __shared__ bf16 tile[32][33];
  const int bh = blockIdx.x, s0 = blockIdx.y*32, d0 = blockIdx.z*32;
  const int b = bh>>4, h = bh&15;
  const int tx = threadIdx.x & 31, ty = threadIdx.x >> 5;
  #pragma unroll
  for (int i=ty;i<32;i+=8)
    tile[i][tx] = vlin[((size_t)(b*1024 + s0+i))*instride + h*128 + d0 + tx];
  __syncthreads();
  #pragma unroll
  for (int i=ty;i<32;i+=8)
    vt[((size_t)(bh*128 + d0+i))*1024 + s0 + tx] = tile[tx][i];
}

// ---------------- flash attention: LDS-staged K/V, double-buffered, XOR-swizzled ----------------
__global__ __launch_bounds__(256) void k_attn(const bf16* __restrict__ Q, const bf16* __restrict__ Kr,
                                              const bf16* __restrict__ Vt, bf16* __restrict__ O)
{
  __shared__ __align__(16) bf16 Kl[2][64*128];
  __shared__ __align__(16) bf16 Vl[2][128*64];
  __shared__ __align__(16) bf16 plds[4][16*64];
  const int t = threadIdx.x, w = t>>6, l = t&63;
  const int bh = blockIdx.x, b = bh>>4, h = bh&15;
  const int q0 = blockIdx.y*64 + w*16;
  const int l4 = l>>4, lc = l&15;

  bf16x8 qf[4];
  const bf16* qbase = Q + ((size_t)(b*1024 + q0 + lc))*2048 + h*128 + l4*8;
  #pragma unroll
  for (int kk=0;kk<4;kk++) qf[kk] = *reinterpret_cast<const bf16x8*>(qbase + kk*32);

  const char* Kg = (const char*)(Kr + ((size_t)(b*1024))*2048 + h*128);
  const char* Vg = (const char*)(Vt + ((size_t)(bh*128))*1024);

  auto stageK = [&](int buf, int kv0) {
    #pragma unroll
    for (int i=0;i<4;i++) {
      const int X = (i*256 + t)*16;
      const int row = X >> 8, colb = X & 255;
      gload_lds16(Kg + (size_t)(kv0+row)*4096 + (colb ^ ((row&7)<<4)), (char*)&Kl[buf][0] + X);
    }
  };
  auto stageV = [&](int buf, int kv0) {
    #pragma unroll
    for (int i=0;i<4;i++) {
      const int X = (i*256 + t)*16;
      const int row = X >> 7, colb = X & 127;
      gload_lds16(Vg + (size_t)row*2048 + kv0*2 + (colb ^ ((row&7)<<4)), (char*)&Vl[buf][0] + X);
    }
  };

  f32x4 oacc[8];
  #pragma unroll
  for (int n=0;n<8;n++) oacc[n]=zero4();
  float mrow[4], lrow[4];
  #pragma unroll
  for (int j=0;j<4;j++){ mrow[j]=-1e30f; lrow[j]=0.f; }
  const float scale = 0.08838834764831845f;

  stageK(0,0); stageV(0,0);
  __syncthreads();
  int cur = 0;

  for (int it=0; it<16; ++it) {
    const int kv0 = it*64;
    if (it < 15) { stageK(cur^1, kv0+64); stageV(cur^1, kv0+64); }

    f32x4 sc[4];
    #pragma unroll
    for (int c=0;c<4;c++) sc[c]=zero4();
    __builtin_amdgcn_s_setprio(1);
    #pragma unroll
    for (int c=0;c<4;c++) {
      const int krow = c*16+lc;
      const char* kp = (const char*)&Kl[cur][0] + krow*256;
      #pragma unroll
      for (int kk=0;kk<4;kk++) {
        bf16x8 kf = *reinterpret_cast<const bf16x8*>(kp + ((kk*64 + l4*16) ^ ((krow&7)<<4)));
        sc[c] = __builtin_amdgcn_mfma_f32_16x16x32_bf16(qf[kk], kf, sc[c], 0,0,0);
      }
    }
    __builtin_amdgcn_s_setprio(0);

    float alpha[4];
    #pragma unroll
    for (int j=0;j<4;j++) {
      float v0=sc[0][j]*scale, v1=sc[1][j]*scale, v2=sc[2][j]*scale, v3=sc[3][j]*scale;
      float mx = fmaxf(fmaxf(v0,v1),fmaxf(v2,v3));
      #pragma unroll
      for (int d=1;d<16;d<<=1) mx = fmaxf(mx, __shfl_xor(mx,d));
      float mn = fmaxf(mrow[j], mx);
      alpha[j] = __expf(mrow[j]-mn);
      mrow[j] = mn;
      float p0=__expf(v0-mn), p1=__expf(v1-mn), p2=__expf(v2-mn), p3=__expf(v3-mn);
      sc[0][j]=p0; sc[1][j]=p1; sc[2][j]=p2; sc[3][j]=p3;
      float ps = (p0+p1)+(p2+p3);
      #pragma unroll
      for (int d=1;d<16;d<<=1) ps += __shfl_xor(ps,d);
      lrow[j] = lrow[j]*alpha[j] + ps;
    }
    #pragma unroll
    for (int n=0;n<8;n++)
      #pragma unroll
      for (int j=0;j<4;j++) oacc[n][j]*=alpha[j];

    char* pw = (char*)&plds[w][0];
    #pragma unroll
    for (int c=0;c<4;c++)
      #pragma unroll
      for (int j=0;j<4;j++) {
        const int qrow = l4*4+j;
        *reinterpret_cast<bf16*>(pw + qrow*128 + ((c*32 + lc*2) ^ ((qrow&7)<<4))) =
            __float2bfloat16(sc[c][j]);
      }
    bf16x8 pf[2];
    #pragma unroll
    for (int ks=0;ks<2;ks++)
      pf[ks] = *reinterpret_cast<const bf16x8*>(pw + lc*128 + ((ks*64 + l4*16) ^ ((lc&7)<<4)));

    __builtin_amdgcn_s_setprio(1);
    #pragma unroll
    for (int n=0;n<8;n++) {
      const int drow = n*16+lc;
      const char* vp = (const char*)&Vl[cur][0] + drow*128;
      #pragma unroll
      for (int ks=0;ks<2;ks++) {
        bf16x8 vf = *reinterpret_cast<const bf16x8*>(vp + ((ks*64 + l4*16) ^ ((drow&7)<<4)));
        oacc[n] = __builtin_amdgcn_mfma_f32_16x16x32_bf16(pf[ks], vf, oacc[n], 0,0,0);
      }
    }
    __builtin_amdgcn_s_setprio(0);

    __syncthreads();
    cur ^= 1;
  }

  #pragma unroll
  for (int n=0;n<8;n++)
    #pragma unroll
    for (int j=0;j<4;j++) {
      float v = oacc[n][j]/lrow[j];
      O[((size_t)(b*1024 + q0 + l4*4 + j))*2048 + h*128 + n*16 + lc] = __float2bfloat16(v);
    }
}

// ---------------- LayerNorm (vectorized): over 2048 cols of (in0 [+in1] [+in2] [+addv(b)]) ----
__global__ __launch_bounds__(256) void k_ln(const float* __restrict__ in0, const float* __restrict__ in1,
                                            const float* __restrict__ in2, const float* __restrict__ addv,
                                            float* __restrict__ outsum,
                                            float* __restrict__ outf, bf16* __restrict__ outb,
                                            const float* __restrict__ g, const float* __restrict__ bta)
{
  const int row = blockIdx.x;
  const int b = row >> 10;
  const size_t base = (size_t)row*2048;
  const int c0 = threadIdx.x * 8;
  f32x4 v0 = *(const f32x4*)(in0 + base + c0);
  f32x4 v1 = *(const f32x4*)(in0 + base + c0 + 4);
  if (in1) { v0 += *(const f32x4*)(in1 + base + c0); v1 += *(const f32x4*)(in1 + base + c0 + 4); }
  if (in2) { v0 += *(const f32x4*)(in2 + base + c0); v1 += *(const f32x4*)(in2 + base + c0 + 4); }
  if (addv){ v0 += *(const f32x4*)(addv + b*2048 + c0); v1 += *(const f32x4*)(addv + b*2048 + c0 + 4); }
  if (outsum) { *(f32x4*)(outsum + base + c0) = v0; *(f32x4*)(outsum + base + c0 + 4) = v1; }
  float s = (v0[0]+v0[1])+(v0[2]+v0[3]) + (v1[0]+v1[1])+(v1[2]+v1[3]);
  __shared__ float red[256];
  red[threadIdx.x]=s; __syncthreads();
  for (int o=128;o>0;o>>=1){ if(threadIdx.x<o) red[threadIdx.x]+=red[threadIdx.x+o]; __syncthreads(); }
  float mean = red[0] * (1.f/2048.f);
  __syncthreads();
  float vs=0.f;
  #pragma unroll
  for (int i=0;i<4;i++){ float d=v0[i]-mean; vs+=d*d; }
  #pragma unroll
  for (int i=0;i<4;i++){ float d=v1[i]-mean; vs+=d*d; }
  red[threadIdx.x]=vs; __syncthreads();
  for (int o=128;o>0;o>>=1){ if(threadIdx.x<o) red[threadIdx.x]+=red[threadIdx.x+o]; __syncthreads(); }
  float inv = rsqrtf(red[0]*(1.f/2048.f) + 1e-5f);
  f32x4 g0 = *(const f32x4*)(g + c0),  g1v = *(const f32x4*)(g + c0 + 4);
  f32x4 b0 = *(const f32x4*)(bta + c0), b1v = *(const f32x4*)(bta + c0 + 4);
  f32x4 r0, r1;
  #pragma unroll
  for (int i=0;i<4;i++) r0[i] = (v0[i]-mean)*inv*g0[i] + b0[i];
  #pragma unroll
  for (int i=0;i<4;i++) r1[i] = (v1[i]-mean)*inv*g1v[i] + b1v[i];
  if (outf) { *(f32x4*)(outf + base + c0) = r0; *(f32x4*)(outf + base + c0 + 4) = r1; }
  if (outb) {
    union { ushort u[8]; uint4 v; } ob;
    #pragma unroll
    for (int i=0;i<4;i++) { ob.u[i] = __bfloat16_as_ushort(__float2bfloat16(r0[i]));
                            ob.u[4+i] = __bfloat16_as_ushort(__float2bfloat16(r1[i])); }
    *reinterpret_cast<uint4*>(outb + base + c0) = ob.v;
  }
}

// ---------------- pool: two-stage, vectorized ----------------
__global__ __launch_bounds__(256) void k_poolp(const float* __restrict__ in0, const float* __restrict__ in1,
                                               const float* __restrict__ in2, float* __restrict__ part) {
  const int ch = blockIdx.x, b = blockIdx.y;
  const int t = threadIdx.x;
  f32x4 a0 = zero4(), a1 = zero4();
  #pragma unroll 4
  for (int r=0;r<16;++r) {
    const size_t base = ((size_t)(b*1024 + ch*16 + r))*2048;
    a0 += *(const f32x4*)(in0 + base + t*4);
    a1 += *(const f32x4*)(in0 + base + 1024 + t*4);
    if (in1) { a0 += *(const f32x4*)(in1 + base + t*4); a1 += *(const f32x4*)(in1 + base + 1024 + t*4); }
    if (in2) { a0 += *(const f32x4*)(in2 + base + t*4); a1 += *(const f32x4*)(in2 + base + 1024 + t*4); }
  }
  float* pp = part + ((size_t)(ch*4 + b))*2048;
  *(f32x4*)(pp + t*4) = a0;
  *(f32x4*)(pp + 1024 + t*4) = a1;
}

__global__ __launch_bounds__(256) void k_pools(const float* __restrict__ part, float* __restrict__ out) {
  const int b = blockIdx.y;
  const int c = blockIdx.x*1024 + threadIdx.x*4;
  f32x4 s = zero4();
  #pragma unroll 8
  for (int ch=0;ch<64;++ch)
    s += *(const f32x4*)(part + ((size_t)(ch*4+b))*2048 + c);
  #pragma unroll
  for (int i=0;i<4;i++) s[i] *= (1.f/1024.f);
  *(f32x4*)(out + b*2048 + c) = s;
}

__global__ __launch_bounds__(256) void k_gate(const float* __restrict__ xp, const float* __restrict__ wg,
                                              const float* __restrict__ bg, const float* __restrict__ tau,
                                              float* __restrict__ hf)
{
  const int n = blockIdx.x*256 + threadIdx.x;
  const int b = blockIdx.y;
  float s = bg[n];
  const float* xr = xp + b*2048;
  for (int k=0;k<2048;k++) s += xr[k]*wg[(size_t)k*2048 + n];
  float gate = 1.f/(1.f+__expf(-s));
  float tf = 0.1f + 9.9f/(1.f+__expf(-tau[n]));
  hf[b*2048+n] = 0.1f*gate*xr[n]/tf;
}

// ---------------- head ----------------
__global__ void k_qm(const float* __restrict__ pooled, const float* __restrict__ w_mp,
                     const float* __restrict__ b_mp, float* __restrict__ qm) {
  int n = blockIdx.x*256 + threadIdx.x;  // 512
  int b = blockIdx.y;
  float s = b_mp[n];
  for (int k=0;k<2048;k++) s += pooled[b*2048+k]*w_mp[(size_t)k*512+n];
  qm[b*512+n]=s;
}

__global__ void k_mscore(const float* __restrict__ qm, const float* __restrict__ bank,
                         float* __restrict__ mattn) {
  int n = blockIdx.x*256 + threadIdx.x;
  if (n >= 10000) return;
  const float sc = 0.04419417382415922f;  // 1/sqrt(512)
  #pragma unroll
  for (int b=0;b<4;b++){
    float s=0.f;
    for (int k=0;k<512;k++) s += qm[b*512+k]*bank[(size_t)n*512+k];
    mattn[b*10000+n] = s*sc;
  }
}

__global__ __launch_bounds__(256) void k_msoftmax(float* __restrict__ mattn) {
  int b = blockIdx.x;
  __shared__ float red[256];
  float mx=-1e30f;
  for (int i=threadIdx.x;i<10000;i+=256) mx=fmaxf(mx, mattn[b*10000+i]);
  red[threadIdx.x]=mx; __syncthreads();
  for (int o=128;o>0;o>>=1){ if(threadIdx.x<o) red[threadIdx.x]=fmaxf(red[threadIdx.x],red[threadIdx.x+o]); __syncthreads(); }
  mx=red[0]; __syncthreads();
  float sm=0.f;
  for (int i=threadIdx.x;i<10000;i+=256){ float e=__expf(mattn[b*10000+i]-mx); mattn[b*10000+i]=e; sm+=e; }
  red[threadIdx.x]=sm; __syncthreads();
  for (int o=128;o>0;o>>=1){ if(threadIdx.x<o) red[threadIdx.x]+=red[threadIdx.x+o]; __syncthreads(); }
  float inv = 1.f/red[0];
  for (int i=threadIdx.x;i<10000;i+=256) mattn[b*10000+i]*=inv;
}

__global__ void k_memmid(const float* __restrict__ mattn, const float* __restrict__ bank,
                         float* __restrict__ part) {
  int d = blockIdx.x*256 + threadIdx.x;  // 512
  int b = blockIdx.y, ch = blockIdx.z;   // 16 chunks x 625
  float s=0.f;
  for (int n=ch*625;n<(ch+1)*625;n++) s += mattn[b*10000+n]*bank[(size_t)n*512+d];
  part[(size_t)ch*2048 + b*512 + d]=s;
}

__global__ void k_midsum(const float* __restrict__ part, float* __restrict__ mid) {
  int i = blockIdx.x*256 + threadIdx.x;  // 2048
  float s=0.f;
  #pragma unroll
  for (int ch=0;ch<16;ch++) s += part[(size_t)ch*2048 + i];
  mid[i]=s;
}

__global__ void k_feat(const float* __restrict__ mid, const float* __restrict__ w_mr,
                       const float* __restrict__ b_mr, const float* __restrict__ pooled,
                       float* __restrict__ feat) {
  int n = blockIdx.x*256 + threadIdx.x;  // 2048
  int b = blockIdx.y;
  float s = b_mr[n];
  for (int d=0;d<512;d++) s += mid[b*512+d]*w_mr[(size_t)d*2048+n];
  feat[b*2048+n] = pooled[b*2048+n] + s;
}

__global__ void k_mlp1(const float* __restrict__ feat, const float* __restrict__ w,
                       const float* __restrict__ bias, float* __restrict__ out) {
  int n = blockIdx.x*256 + threadIdx.x;  // 1024
  int b = blockIdx.y;
  float s = bias[n];
  for (int k=0;k<2048;k++) s += feat[b*2048+k]*w[(size_t)k*1024+n];
  out[b*1024+n] = gelu_f(s);
}

__global__ void k_out(const float* __restrict__ a1, const float* __restrict__ w_a2, const float* __restrict__ b_a2,
                      const float* __restrict__ v1, const float* __restrict__ w_v2, const float* __restrict__ b_v2,
                      float* __restrict__ out) {
  int idx = blockIdx.x*256 + threadIdx.x;  // 1024
  if (idx < 1024) {
    int b = idx>>8, n = idx&255;
    float s = b_a2[n];
    for (int k=0;k<1024;k++) s += a1[b*1024+k]*w_a2[(size_t)k*256+n];
    out[b*256+n]=s;
  }
  if (idx < 4) {
    float s = b_v2[0];
    for (int k=0;k<1024;k++) s += v1[idx*1024+k]*w_v2[k];
    out[1024+idx]=s;
  }
}

extern "C" void kernel_launch(void* const* d_in, const int* in_sizes, int n_in,
                              void* d_out, int out_size, void* d_ws, size_t ws_size,
                              hipStream_t stream)
{
  (void)in_sizes; (void)n_in; (void)out_size;
  const float* x     = (const float*)d_in[0];
  const float* w_in  = (const float*)d_in[1];
  const float* b_in  = (const float*)d_in[2];
  const float* g_in  = (const float*)d_in[3];
  const float* be_in = (const float*)d_in[4];
  const float* wq    = (const float*)d_in[5];
  const float* wk    = (const float*)d_in[6];
  const float* wv    = (const float*)d_in[7];
  const float* wo    = (const float*)d_in[8];
  const float* g1    = (const float*)d_in[11];
  const float* be1   = (const float*)d_in[12];
  const float* g2    = (const float*)d_in[13];
  const float* be2   = (const float*)d_in[14];
  const float* wff1  = (const float*)d_in[15];
  const float* bff1  = (const float*)d_in[16];
  const float* wff2  = (const float*)d_in[17];
  const float* bff2  = (const float*)d_in[18];
  const float* wgate = (const float*)d_in[19];
  const float* bgate = (const float*)d_in[20];
  const float* tauff = (const float*)d_in[21];
  const float* bank  = (const float*)d_in[22];
  const float* w_mp  = (const float*)d_in[23];
  const float* b_mp  = (const float*)d_in[24];
  const float* w_mr  = (const float*)d_in[25];
  const float* b_mr  = (const float*)d_in[26];
  const float* w_a1  = (const float*)d_in[27];
  const float* b_a1  = (const float*)d_in[28];
  const float* w_a2  = (const float*)d_in[29];
  const float* b_a2  = (const float*)d_in[30];
  const float* w_v1  = (const float*)d_in[31];
  const float* b_v1  = (const float*)d_in[32];
  const float* w_v2  = (const float*)d_in[33];
  const float* b_v2  = (const float*)d_in[34];
  float* out = (float*)d_out;

  char* ws = (char*)d_ws;
  size_t o = 0;
  auto alloc = [&](size_t bytes)->char* { char* p = ws + o; o += (bytes + 255) & ~(size_t)255; return p; };
  bf16*  WINT   = (bf16*) alloc(2048ull*1024*2);
  bf16*  WT     = (bf16*) alloc(33554432ull);
  float* XF     = (float*)alloc(33554432ull);
  bf16*  XBF    = (bf16*) alloc(16777216ull);
  float* COS    = (float*)alloc(262144);
  float* SIN    = (float*)alloc(262144);
  float* XP     = (float*)alloc(32768);
  float* HF     = (float*)alloc(32768);
  float* POOLED = (float*)alloc(32768);
  float* QM     = (float*)alloc(8192);
  float* MATTN  = (float*)alloc(160000);
  float* MPART  = (float*)alloc(131072);
  float* MIDS   = (float*)alloc(8192);
  float* FEAT   = (float*)alloc(32768);
  float* A1     = (float*)alloc(16384);
  float* V1     = (float*)alloc(16384);
  float* PPART  = (float*)alloc(2097152);
  bf16*  BUF    = (bf16*) alloc(5ull*16777216);
  float* P0     = (float*)alloc(33554432ull);   // split-K partial 0 (4096x2048 fp32)
  float* P1     = (float*)alloc(33554432ull);   // split-K partial 1
  if (o > ws_size) return;

  const size_t EB = 8388608;
  bf16* QKV = BUF + 0*EB;          // fused q|k|v output, 4096 x 6144, spans BUF0..BUF2
  bf16* QR  = BUF + 3*EB;
  bf16* KR  = BUF + 4*EB;
  bf16* VT  = (bf16*)WT;           // into dead WTq/WTk (after QKV gemm)
  bf16* AO  = BUF + 0*EB;          // reuses QKV after ropes/vtrans
  bf16* MID = BUF + 0*EB;          // ff1 out, spans BUF0..BUF3
  bf16* XINB = BUF + 0*EB;

  bf16* WTq = WT;            bf16* WTk = WT + 4194304;
  bf16* WTv = WT + 8388608;  bf16* WTo = WT + 12582912;

  // ---- prologue ----
  k_cossin<<<256, 256, 0, stream>>>(COS, SIN);
  k_cvt<<<4096, 256, 0, stream>>>(x, XINB, 1048576);
  k_tr64<<<dim3(32,16), 256, 0, stream>>>(w_in, WINT, 1024, 2048);
  k_gemm2<5,4><<<dim3(8,16,2), 512, 0, stream>>>(XINB, WINT, 4096, 2048, 512, 1024, P0, (bf16*)nullptr, b_in);
  k_ln<<<4096, 256, 0, stream>>>(P0, P1, (const float*)nullptr, (const float*)nullptr,
                                 (float*)nullptr, XF, XBF, g_in, be_in);

  for (int i=0;i<2;i++) {
    const size_t ws2 = (size_t)i*2048*2048;
    k_tr64<<<dim3(32,32), 256, 0, stream>>>(wq + ws2, WTq, 2048, 2048);
    k_tr64<<<dim3(32,32), 256, 0, stream>>>(wk + ws2, WTk, 2048, 2048);
    k_tr64<<<dim3(32,32), 256, 0, stream>>>(wv + ws2, WTv, 2048, 2048);
    k_tr64<<<dim3(32,32), 256, 0, stream>>>(wo + ws2, WTo, 2048, 2048);
    // fused QKV projection: N=6144
    k_gemm2<1,6><<<dim3(24,16), 512, 0, stream>>>(XBF, WTq, 4096, 6144, 2048, 2048, (float*)nullptr, QKV, (const float*)nullptr);
    // RoPE + V transpose (VT lives in dead WTq/WTk region)
    k_rope<<<8192, 256, 0, stream>>>(QKV,        6144, QR, COS, SIN);
    k_rope<<<8192, 256, 0, stream>>>(QKV + 2048, 6144, KR, COS, SIN);
    k_vtrans<<<dim3(64,32,4), 256, 0, stream>>>(QKV + 4096, 6144, VT);
    // attention
    k_attn<<<dim3(64,16), 256, 0, stream>>>(QR, KR, VT, AO);
    // output proj, split-K=2 -> P0,P1 ; ln combines x1 = XF+P0+P1, writes back + bf16
    k_gemm2<6,4><<<dim3(8,16,2), 512, 0, stream>>>(AO, WTo, 4096, 2048, 1024, 2048, P0, (bf16*)nullptr, (const float*)nullptr);
    k_ln<<<4096, 256, 0, stream>>>(XF, P0, P1, (const float*)nullptr,
                                   XF, (float*)nullptr, XBF, g1 + i*2048, be1 + i*2048);
    // FFN
    k_tr64<<<dim3(128,32), 256, 0, stream>>>(wff1 + (size_t)i*2048*8192, WT, 2048, 8192);
    k_gemm2<3,8><<<dim3(32,16), 512, 0, stream>>>(XBF, WT, 4096, 8192, 2048, 2048, (float*)nullptr, MID, bff1 + i*8192);
    k_tr64<<<dim3(32,128), 256, 0, stream>>>(wff2 + (size_t)i*8192*2048, WT, 8192, 2048);
    // ff2, split-K=2 (K=8192 -> 2x4096) -> P0 (with bias), P1
    k_gemm2<5,4><<<dim3(8,16,2), 512, 0, stream>>>(MID, WT, 4096, 2048, 4096, 8192, P0, (bf16*)nullptr, bff2 + i*2048);
    // liquid gate + final LN (x2 = XF + P0 + P1)
    k_poolp<<<dim3(64,4), 256, 0, stream>>>(XF, P0, P1, PPART);
    k_pools<<<dim3(2,4), 256, 0, stream>>>(PPART, XP);
    k_gate<<<dim3(8,4), 256, 0, stream>>>(XP, wgate + ws2, bgate + i*2048, tauff + i*2048, HF);
    k_ln<<<4096, 256, 0, stream>>>(XF, P0, P1, HF,
                                   (float*)nullptr, XF, XBF, g2 + i*2048, be2 + i*2048);
  }

  // ---- head ----
  k_poolp<<<dim3(64,4), 256, 0, stream>>>(XF, (const float*)nullptr, (const float*)nullptr, PPART);
  k_pools<<<dim3(2,4), 256, 0, stream>>>(PPART, POOLED);
  k_qm<<<dim3(2,4), 256, 0, stream>>>(POOLED, w_mp, b_mp, QM);
  k_mscore<<<40, 256, 0, stream>>>(QM, bank, MATTN);
  k_msoftmax<<<4, 256, 0, stream>>>(MATTN);
  k_memmid<<<dim3(2,4,16), 256, 0, stream>>>(MATTN, bank, MPART);
  k_midsum<<<8, 256, 0, stream>>>(MPART, MIDS);
  k_feat<<<dim3(8,4), 256, 0, stream>>>(MIDS, w_mr, b_mr, POOLED, FEAT);
  k_mlp1<<<dim3(4,4), 256, 0, stream>>>(FEAT, w_a1, b_a1, A1);
  k_mlp1<<<dim3(4,4), 256, 0, stream>>>(FEAT, w_v1, b_v1, V1);
  k_out<<<4, 256, 0, stream>>>(A1, w_a2, b_a2, V1, w_v2, b_v2, out);
}

// Round 14
// 2314.580 us; speedup vs baseline: 1.0290x; 1.0215x over previous
//
#include <hip/hip_runtime.h>
#include <hip/hip_bf16.h>
#include <math.h>

typedef __hip_bfloat16 bf16;
typedef __bf16 bf16x8 __attribute__((ext_vector_type(8)));
typedef float f32x4 __attribute__((ext_vector_type(4)));

__device__ __forceinline__ f32x4 zero4() { f32x4 z; z[0]=0.f; z[1]=0.f; z[2]=0.f; z[3]=0.f; return z; }

__device__ __forceinline__ void gload_lds16(const void* g, void* l) {
  __builtin_amdgcn_global_load_lds(
      (const __attribute__((address_space(1))) void*)g,
      (__attribute__((address_space(3))) void*)l, 16, 0, 0);
}

__device__ __forceinline__ float gelu_f(float t) {
  return 0.5f*t*(1.0f+erff(t*0.70710678118654752f));
}

// 2D XCD supertile over the (x,y) grid (z excluded).
template<int SW>
__device__ __forceinline__ void xcd_tile(int& bx, int& by) {
  const int gx = gridDim.x;
  const int nwg = gx * gridDim.y;
  const int orig = blockIdx.y * gx + blockIdx.x;
  const int L = nwg >> 3;
  const int c = orig & 7, i = orig >> 3;
  const int gxW = gx / SW;
  const int H = L / SW;
  bx = (c % gxW) * SW + i % SW;
  by = (c / gxW) * H + i / SW;
}

// ---------------- GEMM v10: 8-phase, hoisted addresses, held B operands ----------------
// 256x256 tile, BK=64, 8 waves. 2 K-tiles/iteration; 1 half-tile staged per phase;
// vmcnt(6) only at ph4/ph8. All ds_read addresses = precomputed base + immediate.
// C(MxN) = A(MxK,bf16) * B^T (B is NxK bf16). K2 = K-slice extent, Kstride = row stride.
// MODE 1: outb=acc; 3: outb=gelu(acc+bias); 5: split->outf+z*M*N (z0 adds bias); 6: split->outf
template<int MODE, int SW>
__global__ __launch_bounds__(512, 2) void k_gemm2(
    const bf16* __restrict__ A, const bf16* __restrict__ B,
    int M, int N, int K2, int Kstride,
    float* __restrict__ outf, bf16* __restrict__ outb,
    const float* __restrict__ bias)
{
  // buf: [0,16K) A-lo | [16K,32K) A-hi | [32K,48K) B-lo | [48K,64K) B-hi
  __shared__ __align__(16) char lds[2][65536];
  const int t = threadIdx.x;
  const int w = t>>6, l = t&63;
  const int wr = w>>2, wc = w&3;
  const int lr = l&15, l4 = l>>4, l7 = l&7;

  int bx, by; xcd_tile<SW>(bx, by);
  const int m0 = by*256, n0 = bx*256;

  const int NT = K2 >> 6;                 // even for all shapes used
  const int NJ = NT >> 1;
  const size_t rs = (size_t)Kstride*2;
  const size_t rs64 = rs*64;
  const size_t zoff = (size_t)blockIdx.z * K2 * 2;
  const char* gA = (const char*)A + (size_t)m0*rs + zoff;
  const char* gB = (const char*)B + (size_t)n0*rs + zoff;

  // ---- global stream pointers: one per (buffer, half); advance 256B per j ----
  const int trow = t>>3;
  const size_t swz = (size_t)(((t&7) ^ (trow&7))<<4);
  const char* gAlo = gA + (size_t)trow*rs + swz;
  const char* gAhi = gA + (size_t)(128+trow)*rs + swz;
  const char* gBlo = gB + (size_t)trow*rs + swz;
  const char* gBhi = gB + (size_t)(128+trow)*rs + swz;

  auto STG = [&](const char*& gp, int buf, int which){
    char* d = (char*)lds + buf*65536 + which*16384 + t*16;
    gload_lds16(gp, d);
    gload_lds16(gp + rs64, d + 8192);
    gp += 256;
  };

  // ---- prologue: b0=tile0 (Alo,Bhi,Ahi,Blo), b1=tile1 (Alo,Bhi,Ahi); vmcnt(6) retires b0 ----
  {
    const char* p;
    p = gAlo;       STG(p, 0, 0);
    p = gBhi;       STG(p, 0, 3);
    p = gAhi;       STG(p, 0, 1);
    p = gBlo;       STG(p, 0, 2);
    p = gAlo + 128; STG(p, 1, 0);
    p = gBhi + 128; STG(p, 1, 3);
    p = gAhi + 128; STG(p, 1, 1);
  }
  const char* gp_b1_blo = gBlo + 128;   // next stage: tile 1
  const char* gp_b0_alo = gAlo + 256;   // tile 2
  const char* gp_b0_bhi = gBhi + 256;
  const char* gp_b0_ahi = gAhi + 256;
  const char* gp_b0_blo = gBlo + 256;
  const char* gp_b1_alo = gAlo + 384;   // tile 3
  const char* gp_b1_bhi = gBhi + 384;
  const char* gp_b1_ahi = gAhi + 384;

  // ---- hoisted LDS read base pointers (base + compile-time imm per read) ----
  const int slot0 = l4 ^ l7;
  const int slot1 = (4+l4) ^ l7;
  const char* prA00 = (char*)lds + (wr*64+lr)*128 + slot0*16;
  const char* prA01 = (char*)lds + (wr*64+lr)*128 + slot1*16;
  const char* prB00 = (char*)lds + 32768 + (wc*32+lr)*128 + slot0*16;
  const char* prB01 = (char*)lds + 32768 + (wc*32+lr)*128 + slot1*16;
  const char* prA10 = prA00 + 65536;
  const char* prA11 = prA01 + 65536;
  const char* prB10 = prB00 + 65536;
  const char* prB11 = prB01 + 65536;

  f32x4 acc[2][2][4][2];
  #pragma unroll
  for (int a=0;a<2;a++)
    #pragma unroll
    for (int b=0;b<2;b++)
      #pragma unroll
      for (int c=0;c<4;c++)
        #pragma unroll
        for (int d=0;d<2;d++) acc[a][b][c][d] = zero4();

  bf16x8 aCur[4][2], bLo[2][2], bHi[2][2];
  auto readA = [&](const char* p0, const char* p1, int mhalf){
    #pragma unroll
    for (int mi=0;mi<4;mi++){
      aCur[mi][0] = *reinterpret_cast<const bf16x8*>(p0 + mhalf*16384 + mi*2048);
      aCur[mi][1] = *reinterpret_cast<const bf16x8*>(p1 + mhalf*16384 + mi*2048);
    }
  };
  auto readBlo = [&](const char* p0, const char* p1){
    #pragma unroll
    for (int ni=0;ni<2;ni++){
      bLo[ni][0] = *reinterpret_cast<const bf16x8*>(p0 + ni*2048);
      bLo[ni][1] = *reinterpret_cast<const bf16x8*>(p1 + ni*2048);
    }
  };
  auto readBhi = [&](const char* p0, const char* p1){
    #pragma unroll
    for (int ni=0;ni<2;ni++){
      bHi[ni][0] = *reinterpret_cast<const bf16x8*>(p0 + 16384 + ni*2048);
      bHi[ni][1] = *reinterpret_cast<const bf16x8*>(p1 + 16384 + ni*2048);
    }
  };

  #define BAR do { asm volatile("" ::: "memory"); __builtin_amdgcn_s_barrier(); } while(0)
  #define QMFMA(MH,NH,BSRC)                                                         \
    __builtin_amdgcn_s_setprio(1);                                                  \
    _Pragma("unroll")                                                               \
    for (int mi=0;mi<4;mi++)                                                        \
      _Pragma("unroll")                                                             \
      for (int ni=0;ni<2;ni++)                                                      \
        _Pragma("unroll")                                                           \
        for (int ks=0;ks<2;ks++)                                                    \
          acc[MH][NH][mi][ni] = __builtin_amdgcn_mfma_f32_16x16x32_bf16(            \
              aCur[mi][ks], BSRC[ni][ks], acc[MH][NH][mi][ni], 0,0,0);              \
    __builtin_amdgcn_s_setprio(0);

  asm volatile("s_waitcnt vmcnt(6)" ::: "memory");
  __builtin_amdgcn_s_barrier();

  for (int j=0; j<NJ; ++j) {
    const bool more = (j+1 < NJ);

    // ===== K-tile t0 (buffer 0) =====
    // ph1: read A-lo + B-lo ; stage b1.Blo(t1) ; MFMA(0,0)
    readA(prA00, prA01, 0);
    readBlo(prB00, prB01);
    STG(gp_b1_blo, 1, 2);
    BAR; QMFMA(0,0,bLo); BAR;

    // ph2: read B-hi ; stage b0.Alo(t0+2) ; MFMA(0,1)  [A-lo held]
    readBhi(prB00, prB01);
    if (more) STG(gp_b0_alo, 0, 0);
    BAR; QMFMA(0,1,bHi); BAR;

    // ph3: read A-hi ; stage b0.Bhi(t0+2) ; MFMA(1,1)  [B-hi held]
    readA(prA00, prA01, 1);
    if (more) STG(gp_b0_bhi, 0, 3);
    BAR; QMFMA(1,1,bHi); BAR;

    // ph4: no reads ; stage b0.Ahi(t0+2) ; counted wait -> b1 (t1) landed ; MFMA(1,0) [A-hi, B-lo held]
    if (more) { STG(gp_b0_ahi, 0, 1); asm volatile("s_waitcnt vmcnt(6)" ::: "memory"); }
    else      {                       asm volatile("s_waitcnt vmcnt(0)" ::: "memory"); }
    BAR; QMFMA(1,0,bLo); BAR;

    // ===== K-tile t1 (buffer 1) =====
    // ph5: read A-lo + B-lo ; stage b0.Blo(t0+2) ; MFMA(0,0)
    readA(prA10, prA11, 0);
    readBlo(prB10, prB11);
    if (more) STG(gp_b0_blo, 0, 2);
    BAR; QMFMA(0,0,bLo); BAR;

    // ph6: read B-hi ; stage b1.Alo(t1+2) ; MFMA(0,1)
    readBhi(prB10, prB11);
    if (more) STG(gp_b1_alo, 1, 0);
    BAR; QMFMA(0,1,bHi); BAR;

    // ph7: read A-hi ; stage b1.Bhi(t1+2) ; MFMA(1,1)
    readA(prA10, prA11, 1);
    if (more) STG(gp_b1_bhi, 1, 3);
    BAR; QMFMA(1,1,bHi); BAR;

    // ph8: no reads ; stage b1.Ahi(t1+2) ; counted wait -> b0 (t0+2) landed ; MFMA(1,0)
    if (more) { STG(gp_b1_ahi, 1, 1); asm volatile("s_waitcnt vmcnt(6)" ::: "memory"); }
    BAR; QMFMA(1,0,bLo); BAR;
  }
  #undef QMFMA
  #undef BAR

  const int rbase = m0 + wr*64 + l4*4;
  const int cbase = n0 + wc*32 + lr;
  float* po = (MODE>=5) ? outf + (size_t)blockIdx.z * M * N : outf;
  #pragma unroll
  for (int mh=0;mh<2;mh++)
    #pragma unroll
    for (int nh=0;nh<2;nh++)
      #pragma unroll
      for (int mi=0;mi<4;mi++)
        #pragma unroll
        for (int ni=0;ni<2;ni++) {
          const int col = cbase + nh*128 + ni*16;
          #pragma unroll
          for (int q=0;q<4;q++) {
            const int row = rbase + mh*128 + mi*16 + q;
            const size_t idx = (size_t)row*N + col;
            float v = acc[mh][nh][mi][ni][q];
            if (MODE==1)      outb[idx] = __float2bfloat16(v);
            else if (MODE==3) outb[idx] = __float2bfloat16(gelu_f(v + bias[col]));
            else if (MODE==5) po[idx] = (blockIdx.z==0) ? v + bias[col] : v;
            else if (MODE==6) po[idx] = v;
          }
        }
}

// ---------------- transpose: 64x64 tiles, float4 reads, ushort4 writes ----------------
__global__ __launch_bounds__(256) void k_tr64(const float* __restrict__ in, bf16* __restrict__ out,
                                              int K, int N)
{
  __shared__ float tile[64][65];
  const int n0 = blockIdx.x*64, k0 = blockIdx.y*64;
  const int t = threadIdx.x;
  const int tr = t>>4;
  const int tc = (t&15)*4;
  #pragma unroll
  for (int i=0;i<4;i++) {
    const int k = tr + i*16;
    float4 v = *reinterpret_cast<const float4*>(&in[(size_t)(k0+k)*N + n0 + tc]);
    tile[k][tc+0]=v.x; tile[k][tc+1]=v.y; tile[k][tc+2]=v.z; tile[k][tc+3]=v.w;
  }
  __syncthreads();
  #pragma unroll
  for (int i=0;i<4;i++) {
    const int n = tr + i*16;
    bf16 r[4];
    #pragma unroll
    for (int c=0;c<4;c++) r[c] = __float2bfloat16(tile[tc+c][n]);
    *reinterpret_cast<ushort4*>(&out[(size_t)(n0+n)*K + k0 + tc]) = *reinterpret_cast<const ushort4*>(r);
  }
}

__global__ void k_cvt(const float* __restrict__ in, bf16* __restrict__ out, int n4) {
  int i = blockIdx.x*256 + threadIdx.x;
  if (i < n4) {
    float4 v = reinterpret_cast<const float4*>(in)[i];
    out[i*4+0]=__float2bfloat16(v.x); out[i*4+1]=__float2bfloat16(v.y);
    out[i*4+2]=__float2bfloat16(v.z); out[i*4+3]=__float2bfloat16(v.w);
  }
}

__global__ void k_cossin(float* __restrict__ c, float* __restrict__ s) {
  int idx = blockIdx.x*256 + threadIdx.x;   // 1024*64
  int j = idx & 63, pos = idx >> 6;
  float inv = powf(10000.f, -(float)(2*j)/128.f);
  float a = (float)pos * inv;
  c[idx] = cosf(a); s[idx] = sinf(a);
}

// rope (vectorized): lane j2 handles out dims {2*j2, 2*j2+1} of one (row,head)
__global__ void k_rope(const bf16* __restrict__ in, int instride, bf16* __restrict__ out,
                       const float* __restrict__ cosc, const float* __restrict__ sinc) {
  int idx = blockIdx.x*256 + threadIdx.x;   // 4096*16*32
  int j2 = idx & 31, h = (idx>>5) & 15, row = idx >> 9;
  int s = row & 1023;
  const bf16* rp = in + (size_t)row*instride + h*128 + j2*4;
  union { ushort4 u; bf16 b[4]; } vv;
  vv.u = *reinterpret_cast<const ushort4*>(rp);
  float a0 = __bfloat162float(vv.b[0]), b0 = __bfloat162float(vv.b[1]);
  float a1 = __bfloat162float(vv.b[2]), b1 = __bfloat162float(vv.b[3]);
  const int d = 2*j2;
  float c0 = cosc[s*64+d], s0 = sinc[s*64+d];
  float c1 = cosc[s*64+d+1], s1 = sinc[s*64+d+1];
  bf16* op = out + (size_t)row*2048 + h*128;
  union { ushort2 u; bf16 b[2]; } r0, r1;
  r0.b[0] = __float2bfloat16(a0*c0 - b0*s0);
  r0.b[1] = __float2bfloat16(a1*c1 - b1*s1);
  r1.b[0] = __float2bfloat16(a0*s0 + b0*c0);
  r1.b[1] = __float2bfloat16(a1*s1 + b1*c1);
  *reinterpret_cast<ushort2*>(op + d)      = r0.u;
  *reinterpret_cast<ushort2*>(op + 64 + d) = r1.u;
}

// V (row=b*1024+s of [4096 x instride], col=h*128+d) -> Vt[(bh*128+d)*1024 + s]
__global__ __launch_bounds__(256) void k_vtrans(const bf16* __restrict__ vlin, int instride,
                                                bf16* __restrict__ vt) {
  __shared__ bf16 tile[32][33];
  const int bh = blockIdx.x, s0 = blockIdx.y*32, d0 = blockIdx.z*32;
  const int b = bh>>4, h = bh&15;
  const int tx = threadIdx.x & 31, ty = threadIdx.x >> 5;
  #pragma unroll
  for (int i=ty;i<32;i+=8)
    tile[i][tx] = vlin[((size_t)(b*1024 + s0+i))*instride + h*128 + d0 + tx];
  __syncthreads();
  #pragma unroll
  for (int i=ty;i<32;i+=8)
    vt[((size_t)(bh*128 + d0+i))*1024 + s0 + tx] = tile[tx][i];
}

// ---------------- flash attention: LDS-staged K/V, double-buffered, XOR-swizzled ----------------
__global__ __launch_bounds__(256) void k_attn(const bf16* __restrict__ Q, const bf16* __restrict__ Kr,
                                              const bf16* __restrict__ Vt, bf16* __restrict__ O)
{
  __shared__ __align__(16) bf16 Kl[2][64*128];
  __shared__ __align__(16) bf16 Vl[2][128*64];
  __shared__ __align__(16) bf16 plds[4][16*64];
  const int t = threadIdx.x, w = t>>6, l = t&63;
  const int bh = blockIdx.x, b = bh>>4, h = bh&15;
  const int q0 = blockIdx.y*64 + w*16;
  const int l4 = l>>4, lc = l&15;

  bf16x8 qf[4];
  const bf16* qbase = Q + ((size_t)(b*1024 + q0 + lc))*2048 + h*128 + l4*8;
  #pragma unroll
  for (int kk=0;kk<4;kk++) qf[kk] = *reinterpret_cast<const bf16x8*>(qbase + kk*32);

  const char* Kg = (const char*)(Kr + ((size_t)(b*1024))*2048 + h*128);
  const char* Vg = (const char*)(Vt + ((size_t)(bh*128))*1024);

  auto stageK = [&](int buf, int kv0) {
    #pragma unroll
    for (int i=0;i<4;i++) {
      const int X = (i*256 + t)*16;
      const int row = X >> 8, colb = X & 255;
      gload_lds16(Kg + (size_t)(kv0+row)*4096 + (colb ^ ((row&7)<<4)), (char*)&Kl[buf][0] + X);
    }
  };
  auto stageV = [&](int buf, int kv0) {
    #pragma unroll
    for (int i=0;i<4;i++) {
      const int X = (i*256 + t)*16;
      const int row = X >> 7, colb = X & 127;
      gload_lds16(Vg + (size_t)row*2048 + kv0*2 + (colb ^ ((row&7)<<4)), (char*)&Vl[buf][0] + X);
    }
  };

  f32x4 oacc[8];
  #pragma unroll
  for (int n=0;n<8;n++) oacc[n]=zero4();
  float mrow[4], lrow[4];
  #pragma unroll
  for (int j=0;j<4;j++){ mrow[j]=-1e30f; lrow[j]=0.f; }
  const float scale = 0.08838834764831845f;

  stageK(0,0); stageV(0,0);
  __syncthreads();
  int cur = 0;

  for (int it=0; it<16; ++it) {
    const int kv0 = it*64;
    if (it < 15) { stageK(cur^1, kv0+64); stageV(cur^1, kv0+64); }

    f32x4 sc[4];
    #pragma unroll
    for (int c=0;c<4;c++) sc[c]=zero4();
    __builtin_amdgcn_s_setprio(1);
    #pragma unroll
    for (int c=0;c<4;c++) {
      const int krow = c*16+lc;
      const char* kp = (const char*)&Kl[cur][0] + krow*256;
      #pragma unroll
      for (int kk=0;kk<4;kk++) {
        bf16x8 kf = *reinterpret_cast<const bf16x8*>(kp + ((kk*64 + l4*16) ^ ((krow&7)<<4)));
        sc[c] = __builtin_amdgcn_mfma_f32_16x16x32_bf16(qf[kk], kf, sc[c], 0,0,0);
      }
    }
    __builtin_amdgcn_s_setprio(0);

    float alpha[4];
    #pragma unroll
    for (int j=0;j<4;j++) {
      float v0=sc[0][j]*scale, v1=sc[1][j]*scale, v2=sc[2][j]*scale, v3=sc[3][j]*scale;
      float mx = fmaxf(fmaxf(v0,v1),fmaxf(v2,v3));
      #pragma unroll
      for (int d=1;d<16;d<<=1) mx = fmaxf(mx, __shfl_xor(mx,d));
      float mn = fmaxf(mrow[j], mx);
      alpha[j] = __expf(mrow[j]-mn);
      mrow[j] = mn;
      float p0=__expf(v0-mn), p1=__expf(v1-mn), p2=__expf(v2-mn), p3=__expf(v3-mn);
      sc[0][j]=p0; sc[1][j]=p1; sc[2][j]=p2; sc[3][j]=p3;
      float ps = (p0+p1)+(p2+p3);
      #pragma unroll
      for (int d=1;d<16;d<<=1) ps += __shfl_xor(ps,d);
      lrow[j] = lrow[j]*alpha[j] + ps;
    }
    #pragma unroll
    for (int n=0;n<8;n++)
      #pragma unroll
      for (int j=0;j<4;j++) oacc[n][j]*=alpha[j];

    char* pw = (char*)&plds[w][0];
    #pragma unroll
    for (int c=0;c<4;c++)
      #pragma unroll
      for (int j=0;j<4;j++) {
        const int qrow = l4*4+j;
        *reinterpret_cast<bf16*>(pw + qrow*128 + ((c*32 + lc*2) ^ ((qrow&7)<<4))) =
            __float2bfloat16(sc[c][j]);
      }
    bf16x8 pf[2];
    #pragma unroll
    for (int ks=0;ks<2;ks++)
      pf[ks] = *reinterpret_cast<const bf16x8*>(pw + lc*128 + ((ks*64 + l4*16) ^ ((lc&7)<<4)));

    __builtin_amdgcn_s_setprio(1);
    #pragma unroll
    for (int n=0;n<8;n++) {
      const int drow = n*16+lc;
      const char* vp = (const char*)&Vl[cur][0] + drow*128;
      #pragma unroll
      for (int ks=0;ks<2;ks++) {
        bf16x8 vf = *reinterpret_cast<const bf16x8*>(vp + ((ks*64 + l4*16) ^ ((drow&7)<<4)));
        oacc[n] = __builtin_amdgcn_mfma_f32_16x16x32_bf16(pf[ks], vf, oacc[n], 0,0,0);
      }
    }
    __builtin_amdgcn_s_setprio(0);

    __syncthreads();
    cur ^= 1;
  }

  #pragma unroll
  for (int n=0;n<8;n++)
    #pragma unroll
    for (int j=0;j<4;j++) {
      float v = oacc[n][j]/lrow[j];
      O[((size_t)(b*1024 + q0 + l4*4 + j))*2048 + h*128 + n*16 + lc] = __float2bfloat16(v);
    }
}

// ---------------- LayerNorm (vectorized): over 2048 cols of (in0 [+in1] [+in2] [+addv(b)]) ----
__global__ __launch_bounds__(256) void k_ln(const float* __restrict__ in0, const float* __restrict__ in1,
                                            const float* __restrict__ in2, const float* __restrict__ addv,
                                            float* __restrict__ outsum,
                                            float* __restrict__ outf, bf16* __restrict__ outb,
                                            const float* __restrict__ g, const float* __restrict__ bta)
{
  const int row = blockIdx.x;
  const int b = row >> 10;
  const size_t base = (size_t)row*2048;
  const int c0 = threadIdx.x * 8;
  f32x4 v0 = *(const f32x4*)(in0 + base + c0);
  f32x4 v1 = *(const f32x4*)(in0 + base + c0 + 4);
  if (in1) { v0 += *(const f32x4*)(in1 + base + c0); v1 += *(const f32x4*)(in1 + base + c0 + 4); }
  if (in2) { v0 += *(const f32x4*)(in2 + base + c0); v1 += *(const f32x4*)(in2 + base + c0 + 4); }
  if (addv){ v0 += *(const f32x4*)(addv + b*2048 + c0); v1 += *(const f32x4*)(addv + b*2048 + c0 + 4); }
  if (outsum) { *(f32x4*)(outsum + base + c0) = v0; *(f32x4*)(outsum + base + c0 + 4) = v1; }
  float s = (v0[0]+v0[1])+(v0[2]+v0[3]) + (v1[0]+v1[1])+(v1[2]+v1[3]);
  __shared__ float red[256];
  red[threadIdx.x]=s; __syncthreads();
  for (int o=128;o>0;o>>=1){ if(threadIdx.x<o) red[threadIdx.x]+=red[threadIdx.x+o]; __syncthreads(); }
  float mean = red[0] * (1.f/2048.f);
  __syncthreads();
  float vs=0.f;
  #pragma unroll
  for (int i=0;i<4;i++){ float d=v0[i]-mean; vs+=d*d; }
  #pragma unroll
  for (int i=0;i<4;i++){ float d=v1[i]-mean; vs+=d*d; }
  red[threadIdx.x]=vs; __syncthreads();
  for (int o=128;o>0;o>>=1){ if(threadIdx.x<o) red[threadIdx.x]+=red[threadIdx.x+o]; __syncthreads(); }
  float inv = rsqrtf(red[0]*(1.f/2048.f) + 1e-5f);
  f32x4 g0 = *(const f32x4*)(g + c0),  g1v = *(const f32x4*)(g + c0 + 4);
  f32x4 b0 = *(const f32x4*)(bta + c0), b1v = *(const f32x4*)(bta + c0 + 4);
  f32x4 r0, r1;
  #pragma unroll
  for (int i=0;i<4;i++) r0[i] = (v0[i]-mean)*inv*g0[i] + b0[i];
  #pragma unroll
  for (int i=0;i<4;i++) r1[i] = (v1[i]-mean)*inv*g1v[i] + b1v[i];
  if (outf) { *(f32x4*)(outf + base + c0) = r0; *(f32x4*)(outf + base + c0 + 4) = r1; }
  if (outb) {
    union { ushort u[8]; uint4 v; } ob;
    #pragma unroll
    for (int i=0;i<4;i++) { ob.u[i] = __bfloat16_as_ushort(__float2bfloat16(r0[i]));
                            ob.u[4+i] = __bfloat16_as_ushort(__float2bfloat16(r1[i])); }
    *reinterpret_cast<uint4*>(outb + base + c0) = ob.v;
  }
}

// ---------------- pool: two-stage, vectorized ----------------
__global__ __launch_bounds__(256) void k_poolp(const float* __restrict__ in0, const float* __restrict__ in1,
                                               const float* __restrict__ in2, float* __restrict__ part) {
  const int ch = blockIdx.x, b = blockIdx.y;
  const int t = threadIdx.x;
  f32x4 a0 = zero4(), a1 = zero4();
  #pragma unroll 4
  for (int r=0;r<16;++r) {
    const size_t base = ((size_t)(b*1024 + ch*16 + r))*2048;
    a0 += *(const f32x4*)(in0 + base + t*4);
    a1 += *(const f32x4*)(in0 + base + 1024 + t*4);
    if (in1) { a0 += *(const f32x4*)(in1 + base + t*4); a1 += *(const f32x4*)(in1 + base + 1024 + t*4); }
    if (in2) { a0 += *(const f32x4*)(in2 + base + t*4); a1 += *(const f32x4*)(in2 + base + 1024 + t*4); }
  }
  float* pp = part + ((size_t)(ch*4 + b))*2048;
  *(f32x4*)(pp + t*4) = a0;
  *(f32x4*)(pp + 1024 + t*4) = a1;
}

__global__ __launch_bounds__(256) void k_pools(const float* __restrict__ part, float* __restrict__ out) {
  const int b = blockIdx.y;
  const int c = blockIdx.x*1024 + threadIdx.x*4;
  f32x4 s = zero4();
  #pragma unroll 8
  for (int ch=0;ch<64;++ch)
    s += *(const f32x4*)(part + ((size_t)(ch*4+b))*2048 + c);
  #pragma unroll
  for (int i=0;i<4;i++) s[i] *= (1.f/1024.f);
  *(f32x4*)(out + b*2048 + c) = s;
}

__global__ __launch_bounds__(256) void k_gate(const float* __restrict__ xp, const float* __restrict__ wg,
                                              const float* __restrict__ bg, const float* __restrict__ tau,
                                              float* __restrict__ hf)
{
  const int n = blockIdx.x*256 + threadIdx.x;
  const int b = blockIdx.y;
  float s = bg[n];
  const float* xr = xp + b*2048;
  for (int k=0;k<2048;k++) s += xr[k]*wg[(size_t)k*2048 + n];
  float gate = 1.f/(1.f+__expf(-s));
  float tf = 0.1f + 9.9f/(1.f+__expf(-tau[n]));
  hf[b*2048+n] = 0.1f*gate*xr[n]/tf;
}

// ---------------- head ----------------
__global__ void k_qm(const float* __restrict__ pooled, const float* __restrict__ w_mp,
                     const float* __restrict__ b_mp, float* __restrict__ qm) {
  int n = blockIdx.x*256 + threadIdx.x;  // 512
  int b = blockIdx.y;
  float s = b_mp[n];
  for (int k=0;k<2048;k++) s += pooled[b*2048+k]*w_mp[(size_t)k*512+n];
  qm[b*512+n]=s;
}

__global__ void k_mscore(const float* __restrict__ qm, const float* __restrict__ bank,
                         float* __restrict__ mattn) {
  int n = blockIdx.x*256 + threadIdx.x;
  if (n >= 10000) return;
  const float sc = 0.04419417382415922f;  // 1/sqrt(512)
  #pragma unroll
  for (int b=0;b<4;b++){
    float s=0.f;
    for (int k=0;k<512;k++) s += qm[b*512+k]*bank[(size_t)n*512+k];
    mattn[b*10000+n] = s*sc;
  }
}

__global__ __launch_bounds__(256) void k_msoftmax(float* __restrict__ mattn) {
  int b = blockIdx.x;
  __shared__ float red[256];
  float mx=-1e30f;
  for (int i=threadIdx.x;i<10000;i+=256) mx=fmaxf(mx, mattn[b*10000+i]);
  red[threadIdx.x]=mx; __syncthreads();
  for (int o=128;o>0;o>>=1){ if(threadIdx.x<o) red[threadIdx.x]=fmaxf(red[threadIdx.x],red[threadIdx.x+o]); __syncthreads(); }
  mx=red[0]; __syncthreads();
  float sm=0.f;
  for (int i=threadIdx.x;i<10000;i+=256){ float e=__expf(mattn[b*10000+i]-mx); mattn[b*10000+i]=e; sm+=e; }
  red[threadIdx.x]=sm; __syncthreads();
  for (int o=128;o>0;o>>=1){ if(threadIdx.x<o) red[threadIdx.x]+=red[threadIdx.x+o]; __syncthreads(); }
  float inv = 1.f/red[0];
  for (int i=threadIdx.x;i<10000;i+=256) mattn[b*10000+i]*=inv;
}

__global__ void k_memmid(const float* __restrict__ mattn, const float* __restrict__ bank,
                         float* __restrict__ part) {
  int d = blockIdx.x*256 + threadIdx.x;  // 512
  int b = blockIdx.y, ch = blockIdx.z;   // 16 chunks x 625
  float s=0.f;
  for (int n=ch*625;n<(ch+1)*625;n++) s += mattn[b*10000+n]*bank[(size_t)n*512+d];
  part[(size_t)ch*2048 + b*512 + d]=s;
}

__global__ void k_midsum(const float* __restrict__ part, float* __restrict__ mid) {
  int i = blockIdx.x*256 + threadIdx.x;  // 2048
  float s=0.f;
  #pragma unroll
  for (int ch=0;ch<16;ch++) s += part[(size_t)ch*2048 + i];
  mid[i]=s;
}

__global__ void k_feat(const float* __restrict__ mid, const float* __restrict__ w_mr,
                       const float* __restrict__ b_mr, const float* __restrict__ pooled,
                       float* __restrict__ feat) {
  int n = blockIdx.x*256 + threadIdx.x;  // 2048
  int b = blockIdx.y;
  float s = b_mr[n];
  for (int d=0;d<512;d++) s += mid[b*512+d]*w_mr[(size_t)d*2048+n];
  feat[b*2048+n] = pooled[b*2048+n] + s;
}

__global__ void k_mlp1(const float* __restrict__ feat, const float* __restrict__ w,
                       const float* __restrict__ bias, float* __restrict__ out) {
  int n = blockIdx.x*256 + threadIdx.x;  // 1024
  int b = blockIdx.y;
  float s = bias[n];
  for (int k=0;k<2048;k++) s += feat[b*2048+k]*w[(size_t)k*1024+n];
  out[b*1024+n] = gelu_f(s);
}

__global__ void k_out(const float* __restrict__ a1, const float* __restrict__ w_a2, const float* __restrict__ b_a2,
                      const float* __restrict__ v1, const float* __restrict__ w_v2, const float* __restrict__ b_v2,
                      float* __restrict__ out) {
  int idx = blockIdx.x*256 + threadIdx.x;  // 1024
  if (idx < 1024) {
    int b = idx>>8, n = idx&255;
    float s = b_a2[n];
    for (int k=0;k<1024;k++) s += a1[b*1024+k]*w_a2[(size_t)k*256+n];
    out[b*256+n]=s;
  }
  if (idx < 4) {
    float s = b_v2[0];
    for (int k=0;k<1024;k++) s += v1[idx*1024+k]*w_v2[k];
    out[1024+idx]=s;
  }
}

extern "C" void kernel_launch(void* const* d_in, const int* in_sizes, int n_in,
                              void* d_out, int out_size, void* d_ws, size_t ws_size,
                              hipStream_t stream)
{
  (void)in_sizes; (void)n_in; (void)out_size;
  const float* x     = (const float*)d_in[0];
  const float* w_in  = (const float*)d_in[1];
  const float* b_in  = (const float*)d_in[2];
  const float* g_in  = (const float*)d_in[3];
  const float* be_in = (const float*)d_in[4];
  const float* wq    = (const float*)d_in[5];
  const float* wk    = (const float*)d_in[6];
  const float* wv    = (const float*)d_in[7];
  const float* wo    = (const float*)d_in[8];
  const float* g1    = (const float*)d_in[11];
  const float* be1   = (const float*)d_in[12];
  const float* g2    = (const float*)d_in[13];
  const float* be2   = (const float*)d_in[14];
  const float* wff1  = (const float*)d_in[15];
  const float* bff1  = (const float*)d_in[16];
  const float* wff2  = (const float*)d_in[17];
  const float* bff2  = (const float*)d_in[18];
  const float* wgate = (const float*)d_in[19];
  const float* bgate = (const float*)d_in[20];
  const float* tauff = (const float*)d_in[21];
  const float* bank  = (const float*)d_in[22];
  const float* w_mp  = (const float*)d_in[23];
  const float* b_mp  = (const float*)d_in[24];
  const float* w_mr  = (const float*)d_in[25];
  const float* b_mr  = (const float*)d_in[26];
  const float* w_a1  = (const float*)d_in[27];
  const float* b_a1  = (const float*)d_in[28];
  const float* w_a2  = (const float*)d_in[29];
  const float* b_a2  = (const float*)d_in[30];
  const float* w_v1  = (const float*)d_in[31];
  const float* b_v1  = (const float*)d_in[32];
  const float* w_v2  = (const float*)d_in[33];
  const float* b_v2  = (const float*)d_in[34];
  float* out = (float*)d_out;

  char* ws = (char*)d_ws;
  size_t o = 0;
  auto alloc = [&](size_t bytes)->char* { char* p = ws + o; o += (bytes + 255) & ~(size_t)255; return p; };
  bf16*  WINT   = (bf16*) alloc(2048ull*1024*2);
  bf16*  WT     = (bf16*) alloc(33554432ull);
  float* XF     = (float*)alloc(33554432ull);
  bf16*  XBF    = (bf16*) alloc(16777216ull);
  float* COS    = (float*)alloc(262144);
  float* SIN    = (float*)alloc(262144);
  float* XP     = (float*)alloc(32768);
  float* HF     = (float*)alloc(32768);
  float* POOLED = (float*)alloc(32768);
  float* QM     = (float*)alloc(8192);
  float* MATTN  = (float*)alloc(160000);
  float* MPART  = (float*)alloc(131072);
  float* MIDS   = (float*)alloc(8192);
  float* FEAT   = (float*)alloc(32768);
  float* A1     = (float*)alloc(16384);
  float* V1     = (float*)alloc(16384);
  float* PPART  = (float*)alloc(2097152);
  bf16*  BUF    = (bf16*) alloc(5ull*16777216);
  float* P0     = (float*)alloc(33554432ull);   // split-K partial 0 (4096x2048 fp32)
  float* P1     = (float*)alloc(33554432ull);   // split-K partial 1
  if (o > ws_size) return;

  const size_t EB = 8388608;
  bf16* QKV = BUF + 0*EB;          // fused q|k|v output, 4096 x 6144, spans BUF0..BUF2
  bf16* QR  = BUF + 3*EB;
  bf16* KR  = BUF + 4*EB;
  bf16* VT  = (bf16*)WT;           // into dead WTq/WTk (after QKV gemm)
  bf16* AO  = BUF + 0*EB;          // reuses QKV after ropes/vtrans
  bf16* MID = BUF + 0*EB;          // ff1 out, spans BUF0..BUF3
  bf16* XINB = BUF + 0*EB;

  bf16* WTq = WT;            bf16* WTk = WT + 4194304;
  bf16* WTv = WT + 8388608;  bf16* WTo = WT + 12582912;

  // ---- prologue ----
  k_cossin<<<256, 256, 0, stream>>>(COS, SIN);
  k_cvt<<<4096, 256, 0, stream>>>(x, XINB, 1048576);
  k_tr64<<<dim3(32,16), 256, 0, stream>>>(w_in, WINT, 1024, 2048);
  k_gemm2<5,4><<<dim3(8,16,2), 512, 0, stream>>>(XINB, WINT, 4096, 2048, 512, 1024, P0, (bf16*)nullptr, b_in);
  k_ln<<<4096, 256, 0, stream>>>(P0, P1, (const float*)nullptr, (const float*)nullptr,
                                 (float*)nullptr, XF, XBF, g_in, be_in);

  for (int i=0;i<2;i++) {
    const size_t ws2 = (size_t)i*2048*2048;
    k_tr64<<<dim3(32,32), 256, 0, stream>>>(wq + ws2, WTq, 2048, 2048);
    k_tr64<<<dim3(32,32), 256, 0, stream>>>(wk + ws2, WTk, 2048, 2048);
    k_tr64<<<dim3(32,32), 256, 0, stream>>>(wv + ws2, WTv, 2048, 2048);
    k_tr64<<<dim3(32,32), 256, 0, stream>>>(wo + ws2, WTo, 2048, 2048);
    // fused QKV projection: N=6144
    k_gemm2<1,6><<<dim3(24,16), 512, 0, stream>>>(XBF, WTq, 4096, 6144, 2048, 2048, (float*)nullptr, QKV, (const float*)nullptr);
    // RoPE + V transpose (VT lives in dead WTq/WTk region)
    k_rope<<<8192, 256, 0, stream>>>(QKV,        6144, QR, COS, SIN);
    k_rope<<<8192, 256, 0, stream>>>(QKV + 2048, 6144, KR, COS, SIN);
    k_vtrans<<<dim3(64,32,4), 256, 0, stream>>>(QKV + 4096, 6144, VT);
    // attention
    k_attn<<<dim3(64,16), 256, 0, stream>>>(QR, KR, VT, AO);
    // output proj, split-K=2 -> P0,P1 ; ln combines x1 = XF+P0+P1, writes back + bf16
    k_gemm2<6,4><<<dim3(8,16,2), 512, 0, stream>>>(AO, WTo, 4096, 2048, 1024, 2048, P0, (bf16*)nullptr, (const float*)nullptr);
    k_ln<<<4096, 256, 0, stream>>>(XF, P0, P1, (const float*)nullptr,
                                   XF, (float*)nullptr, XBF, g1 + i*2048, be1 + i*2048);
    // FFN
    k_tr64<<<dim3(128,32), 256, 0, stream>>>(wff1 + (size_t)i*2048*8192, WT, 2048, 8192);
    k_gemm2<3,8><<<dim3(32,16), 512, 0, stream>>>(XBF, WT, 4096, 8192, 2048, 2048, (float*)nullptr, MID, bff1 + i*8192);
    k_tr64<<<dim3(32,128), 256, 0, stream>>>(wff2 + (size_t)i*8192*2048, WT, 8192, 2048);
    // ff2, split-K=2 (K=8192 -> 2x4096) -> P0 (with bias), P1
    k_gemm2<5,4><<<dim3(8,16,2), 512, 0, stream>>>(MID, WT, 4096, 2048, 4096, 8192, P0, (bf16*)nullptr, bff2 + i*2048);
    // liquid gate + final LN (x2 = XF + P0 + P1)
    k_poolp<<<dim3(64,4), 256, 0, stream>>>(XF, P0, P1, PPART);
    k_pools<<<dim3(2,4), 256, 0, stream>>>(PPART, XP);
    k_gate<<<dim3(8,4), 256, 0, stream>>>(XP, wgate + ws2, bgate + i*2048, tauff + i*2048, HF);
    k_ln<<<4096, 256, 0, stream>>>(XF, P0, P1, HF,
                                   (float*)nullptr, XF, XBF, g2 + i*2048, be2 + i*2048);
  }

  // ---- head ----
  k_poolp<<<dim3(64,4), 256, 0, stream>>>(XF, (const float*)nullptr, (const float*)nullptr, PPART);
  k_pools<<<dim3(2,4), 256, 0, stream>>>(PPART, POOLED);
  k_qm<<<dim3(2,4), 256, 0, stream>>>(POOLED, w_mp, b_mp, QM);
  k_mscore<<<40, 256, 0, stream>>>(QM, bank, MATTN);
  k_msoftmax<<<4, 256, 0, stream>>>(MATTN);
  k_memmid<<<dim3(2,4,16), 256, 0, stream>>>(MATTN, bank, MPART);
  k_midsum<<<8, 256, 0, stream>>>(MPART, MIDS);
  k_feat<<<dim3(8,4), 256, 0, stream>>>(MIDS, w_mr, b_mr, POOLED, FEAT);
  k_mlp1<<<dim3(4,4), 256, 0, stream>>>(FEAT, w_a1, b_a1, A1);
  k_mlp1<<<dim3(4,4), 256, 0, stream>>>(FEAT, w_v1, b_v1, V1);
  k_out<<<4, 256, 0, stream>>>(A1, w_a2, b_a2, V1, w_v2, b_v2, out);
}

// Round 15
// 1765.607 us; speedup vs baseline: 1.3490x; 1.3109x over previous
//
#include <hip/hip_runtime.h>
#include <hip/hip_bf16.h>
#include <math.h>

typedef __hip_bfloat16 bf16;
typedef __bf16 bf16x8 __attribute__((ext_vector_type(8)));
typedef float f32x4 __attribute__((ext_vector_type(4)));

__device__ __forceinline__ f32x4 zero4() { f32x4 z; z[0]=0.f; z[1]=0.f; z[2]=0.f; z[3]=0.f; return z; }

__device__ __forceinline__ void gload_lds16(const void* g, void* l) {
  __builtin_amdgcn_global_load_lds(
      (const __attribute__((address_space(1))) void*)g,
      (__attribute__((address_space(3))) void*)l, 16, 0, 0);
}

__device__ __forceinline__ float gelu_f(float t) {
  return 0.5f*t*(1.0f+erff(t*0.70710678118654752f));
}

// 2D XCD supertile over the (x,y) grid (z excluded).
template<int SW>
__device__ __forceinline__ void xcd_tile(int& bx, int& by) {
  const int gx = gridDim.x;
  const int nwg = gx * gridDim.y;
  const int orig = blockIdx.y * gx + blockIdx.x;
  const int L = nwg >> 3;
  const int c = orig & 7, i = orig >> 3;
  const int gxW = gx / SW;
  const int H = L / SW;
  bx = (c % gxW) * SW + i % SW;
  by = (c / gxW) * H + i / SW;
}

// ---------------- GEMM v10: 8-phase, hoisted addresses, held B operands ----------------
// 256x256 tile, BK=64, 8 waves. 2 K-tiles/iteration; 1 half-tile staged per phase;
// vmcnt(6) only at ph4/ph8. All ds_read addresses = precomputed base + immediate.
// MODE 1: outb=acc; 3: outb=gelu(acc+bias); 5: split->outf+z*M*N (z0 adds bias); 6: split->outf
template<int MODE, int SW>
__global__ __launch_bounds__(512, 2) void k_gemm2(
    const bf16* __restrict__ A, const bf16* __restrict__ B,
    int M, int N, int K2, int Kstride,
    float* __restrict__ outf, bf16* __restrict__ outb,
    const float* __restrict__ bias)
{
  __shared__ __align__(16) char lds[2][65536];
  const int t = threadIdx.x;
  const int w = t>>6, l = t&63;
  const int wr = w>>2, wc = w&3;
  const int lr = l&15, l4 = l>>4, l7 = l&7;

  int bx, by; xcd_tile<SW>(bx, by);
  const int m0 = by*256, n0 = bx*256;

  const int NT = K2 >> 6;
  const int NJ = NT >> 1;
  const size_t rs = (size_t)Kstride*2;
  const size_t rs64 = rs*64;
  const size_t zoff = (size_t)blockIdx.z * K2 * 2;
  const char* gA = (const char*)A + (size_t)m0*rs + zoff;
  const char* gB = (const char*)B + (size_t)n0*rs + zoff;

  const int trow = t>>3;
  const size_t swz = (size_t)(((t&7) ^ (trow&7))<<4);
  const char* gAlo = gA + (size_t)trow*rs + swz;
  const char* gAhi = gA + (size_t)(128+trow)*rs + swz;
  const char* gBlo = gB + (size_t)trow*rs + swz;
  const char* gBhi = gB + (size_t)(128+trow)*rs + swz;

  auto STG = [&](const char*& gp, int buf, int which){
    char* d = (char*)lds + buf*65536 + which*16384 + t*16;
    gload_lds16(gp, d);
    gload_lds16(gp + rs64, d + 8192);
    gp += 256;
  };

  {
    const char* p;
    p = gAlo;       STG(p, 0, 0);
    p = gBhi;       STG(p, 0, 3);
    p = gAhi;       STG(p, 0, 1);
    p = gBlo;       STG(p, 0, 2);
    p = gAlo + 128; STG(p, 1, 0);
    p = gBhi + 128; STG(p, 1, 3);
    p = gAhi + 128; STG(p, 1, 1);
  }
  const char* gp_b1_blo = gBlo + 128;
  const char* gp_b0_alo = gAlo + 256;
  const char* gp_b0_bhi = gBhi + 256;
  const char* gp_b0_ahi = gAhi + 256;
  const char* gp_b0_blo = gBlo + 256;
  const char* gp_b1_alo = gAlo + 384;
  const char* gp_b1_bhi = gBhi + 384;
  const char* gp_b1_ahi = gAhi + 384;

  const int slot0 = l4 ^ l7;
  const int slot1 = (4+l4) ^ l7;
  const char* prA00 = (char*)lds + (wr*64+lr)*128 + slot0*16;
  const char* prA01 = (char*)lds + (wr*64+lr)*128 + slot1*16;
  const char* prB00 = (char*)lds + 32768 + (wc*32+lr)*128 + slot0*16;
  const char* prB01 = (char*)lds + 32768 + (wc*32+lr)*128 + slot1*16;
  const char* prA10 = prA00 + 65536;
  const char* prA11 = prA01 + 65536;
  const char* prB10 = prB00 + 65536;
  const char* prB11 = prB01 + 65536;

  f32x4 acc[2][2][4][2];
  #pragma unroll
  for (int a=0;a<2;a++)
    #pragma unroll
    for (int b=0;b<2;b++)
      #pragma unroll
      for (int c=0;c<4;c++)
        #pragma unroll
        for (int d=0;d<2;d++) acc[a][b][c][d] = zero4();

  bf16x8 aCur[4][2], bLo[2][2], bHi[2][2];
  auto readA = [&](const char* p0, const char* p1, int mhalf){
    #pragma unroll
    for (int mi=0;mi<4;mi++){
      aCur[mi][0] = *reinterpret_cast<const bf16x8*>(p0 + mhalf*16384 + mi*2048);
      aCur[mi][1] = *reinterpret_cast<const bf16x8*>(p1 + mhalf*16384 + mi*2048);
    }
  };
  auto readBlo = [&](const char* p0, const char* p1){
    #pragma unroll
    for (int ni=0;ni<2;ni++){
      bLo[ni][0] = *reinterpret_cast<const bf16x8*>(p0 + ni*2048);
      bLo[ni][1] = *reinterpret_cast<const bf16x8*>(p1 + ni*2048);
    }
  };
  auto readBhi = [&](const char* p0, const char* p1){
    #pragma unroll
    for (int ni=0;ni<2;ni++){
      bHi[ni][0] = *reinterpret_cast<const bf16x8*>(p0 + 16384 + ni*2048);
      bHi[ni][1] = *reinterpret_cast<const bf16x8*>(p1 + 16384 + ni*2048);
    }
  };

  #define BAR do { asm volatile("" ::: "memory"); __builtin_amdgcn_s_barrier(); } while(0)
  #define QMFMA(MH,NH,BSRC)                                                         \
    __builtin_amdgcn_s_setprio(1);                                                  \
    _Pragma("unroll")                                                               \
    for (int mi=0;mi<4;mi++)                                                        \
      _Pragma("unroll")                                                             \
      for (int ni=0;ni<2;ni++)                                                      \
        _Pragma("unroll")                                                           \
        for (int ks=0;ks<2;ks++)                                                    \
          acc[MH][NH][mi][ni] = __builtin_amdgcn_mfma_f32_16x16x32_bf16(            \
              aCur[mi][ks], BSRC[ni][ks], acc[MH][NH][mi][ni], 0,0,0);              \
    __builtin_amdgcn_s_setprio(0);

  asm volatile("s_waitcnt vmcnt(6)" ::: "memory");
  __builtin_amdgcn_s_barrier();

  for (int j=0; j<NJ; ++j) {
    const bool more = (j+1 < NJ);

    readA(prA00, prA01, 0);
    readBlo(prB00, prB01);
    STG(gp_b1_blo, 1, 2);
    BAR; QMFMA(0,0,bLo); BAR;

    readBhi(prB00, prB01);
    if (more) STG(gp_b0_alo, 0, 0);
    BAR; QMFMA(0,1,bHi); BAR;

    readA(prA00, prA01, 1);
    if (more) STG(gp_b0_bhi, 0, 3);
    BAR; QMFMA(1,1,bHi); BAR;

    if (more) { STG(gp_b0_ahi, 0, 1); asm volatile("s_waitcnt vmcnt(6)" ::: "memory"); }
    else      {                       asm volatile("s_waitcnt vmcnt(0)" ::: "memory"); }
    BAR; QMFMA(1,0,bLo); BAR;

    readA(prA10, prA11, 0);
    readBlo(prB10, prB11);
    if (more) STG(gp_b0_blo, 0, 2);
    BAR; QMFMA(0,0,bLo); BAR;

    readBhi(prB10, prB11);
    if (more) STG(gp_b1_alo, 1, 0);
    BAR; QMFMA(0,1,bHi); BAR;

    readA(prA10, prA11, 1);
    if (more) STG(gp_b1_bhi, 1, 3);
    BAR; QMFMA(1,1,bHi); BAR;

    if (more) { STG(gp_b1_ahi, 1, 1); asm volatile("s_waitcnt vmcnt(6)" ::: "memory"); }
    BAR; QMFMA(1,0,bLo); BAR;
  }
  #undef QMFMA
  #undef BAR

  const int rbase = m0 + wr*64 + l4*4;
  const int cbase = n0 + wc*32 + lr;
  float* po = (MODE>=5) ? outf + (size_t)blockIdx.z * M * N : outf;
  #pragma unroll
  for (int mh=0;mh<2;mh++)
    #pragma unroll
    for (int nh=0;nh<2;nh++)
      #pragma unroll
      for (int mi=0;mi<4;mi++)
        #pragma unroll
        for (int ni=0;ni<2;ni++) {
          const int col = cbase + nh*128 + ni*16;
          #pragma unroll
          for (int q=0;q<4;q++) {
            const int row = rbase + mh*128 + mi*16 + q;
            const size_t idx = (size_t)row*N + col;
            float v = acc[mh][nh][mi][ni][q];
            if (MODE==1)      outb[idx] = __float2bfloat16(v);
            else if (MODE==3) outb[idx] = __float2bfloat16(gelu_f(v + bias[col]));
            else if (MODE==5) po[idx] = (blockIdx.z==0) ? v + bias[col] : v;
            else if (MODE==6) po[idx] = v;
          }
        }
}

// ---------------- transpose: 64x64 tiles, float4 reads, ushort4 writes ----------------
__global__ __launch_bounds__(256) void k_tr64(const float* __restrict__ in, bf16* __restrict__ out,
                                              int K, int N)
{
  __shared__ float tile[64][65];
  const int n0 = blockIdx.x*64, k0 = blockIdx.y*64;
  const int t = threadIdx.x;
  const int tr = t>>4;
  const int tc = (t&15)*4;
  #pragma unroll
  for (int i=0;i<4;i++) {
    const int k = tr + i*16;
    float4 v = *reinterpret_cast<const float4*>(&in[(size_t)(k0+k)*N + n0 + tc]);
    tile[k][tc+0]=v.x; tile[k][tc+1]=v.y; tile[k][tc+2]=v.z; tile[k][tc+3]=v.w;
  }
  __syncthreads();
  #pragma unroll
  for (int i=0;i<4;i++) {
    const int n = tr + i*16;
    bf16 r[4];
    #pragma unroll
    for (int c=0;c<4;c++) r[c] = __float2bfloat16(tile[tc+c][n]);
    *reinterpret_cast<ushort4*>(&out[(size_t)(n0+n)*K + k0 + tc]) = *reinterpret_cast<const ushort4*>(r);
  }
}

__global__ void k_cvt(const float* __restrict__ in, bf16* __restrict__ out, int n4) {
  int i = blockIdx.x*256 + threadIdx.x;
  if (i < n4) {
    float4 v = reinterpret_cast<const float4*>(in)[i];
    out[i*4+0]=__float2bfloat16(v.x); out[i*4+1]=__float2bfloat16(v.y);
    out[i*4+2]=__float2bfloat16(v.z); out[i*4+3]=__float2bfloat16(v.w);
  }
}

__global__ void k_cossin(float* __restrict__ c, float* __restrict__ s) {
  int idx = blockIdx.x*256 + threadIdx.x;   // 1024*64
  int j = idx & 63, pos = idx >> 6;
  float inv = powf(10000.f, -(float)(2*j)/128.f);
  float a = (float)pos * inv;
  c[idx] = cosf(a); s[idx] = sinf(a);
}

// rope (vectorized): lane j2 handles out dims {2*j2, 2*j2+1} of one (row,head)
__global__ void k_rope(const bf16* __restrict__ in, int instride, bf16* __restrict__ out,
                       const float* __restrict__ cosc, const float* __restrict__ sinc) {
  int idx = blockIdx.x*256 + threadIdx.x;   // 4096*16*32
  int j2 = idx & 31, h = (idx>>5) & 15, row = idx >> 9;
  int s = row & 1023;
  const bf16* rp = in + (size_t)row*instride + h*128 + j2*4;
  union { ushort4 u; bf16 b[4]; } vv;
  vv.u = *reinterpret_cast<const ushort4*>(rp);
  float a0 = __bfloat162float(vv.b[0]), b0 = __bfloat162float(vv.b[1]);
  float a1 = __bfloat162float(vv.b[2]), b1 = __bfloat162float(vv.b[3]);
  const int d = 2*j2;
  float c0 = cosc[s*64+d], s0 = sinc[s*64+d];
  float c1 = cosc[s*64+d+1], s1 = sinc[s*64+d+1];
  bf16* op = out + (size_t)row*2048 + h*128;
  union { ushort2 u; bf16 b[2]; } r0, r1;
  r0.b[0] = __float2bfloat16(a0*c0 - b0*s0);
  r0.b[1] = __float2bfloat16(a1*c1 - b1*s1);
  r1.b[0] = __float2bfloat16(a0*s0 + b0*c0);
  r1.b[1] = __float2bfloat16(a1*s1 + b1*c1);
  *reinterpret_cast<ushort2*>(op + d)      = r0.u;
  *reinterpret_cast<ushort2*>(op + 64 + d) = r1.u;
}

// V (row=b*1024+s of [4096 x instride], col=h*128+d) -> Vt[(bh*128+d)*1024 + s]
__global__ __launch_bounds__(256) void k_vtrans(const bf16* __restrict__ vlin, int instride,
                                                bf16* __restrict__ vt) {
  __shared__ bf16 tile[32][33];
  const int bh = blockIdx.x, s0 = blockIdx.y*32, d0 = blockIdx.z*32;
  const int b = bh>>4, h = bh&15;
  const int tx = threadIdx.x & 31, ty = threadIdx.x >> 5;
  #pragma unroll
  for (int i=ty;i<32;i+=8)
    tile[i][tx] = vlin[((size_t)(b*1024 + s0+i))*instride + h*128 + d0 + tx];
  __syncthreads();
  #pragma unroll
  for (int i=ty;i<32;i+=8)
    vt[((size_t)(bh*128 + d0+i))*1024 + s0 + tx] = tile[tx][i];
}

// ---------------- flash attention: LDS-staged K/V, double-buffered, XOR-swizzled ----------------
__global__ __launch_bounds__(256) void k_attn(const bf16* __restrict__ Q, const bf16* __restrict__ Kr,
                                              const bf16* __restrict__ Vt, bf16* __restrict__ O)
{
  __shared__ __align__(16) bf16 Kl[2][64*128];
  __shared__ __align__(16) bf16 Vl[2][128*64];
  __shared__ __align__(16) bf16 plds[4][16*64];
  const int t = threadIdx.x, w = t>>6, l = t&63;
  const int bh = blockIdx.x, b = bh>>4, h = bh&15;
  const int q0 = blockIdx.y*64 + w*16;
  const int l4 = l>>4, lc = l&15;

  bf16x8 qf[4];
  const bf16* qbase = Q + ((size_t)(b*1024 + q0 + lc))*2048 + h*128 + l4*8;
  #pragma unroll
  for (int kk=0;kk<4;kk++) qf[kk] = *reinterpret_cast<const bf16x8*>(qbase + kk*32);

  const char* Kg = (const char*)(Kr + ((size_t)(b*1024))*2048 + h*128);
  const char* Vg = (const char*)(Vt + ((size_t)(bh*128))*1024);

  auto stageK = [&](int buf, int kv0) {
    #pragma unroll
    for (int i=0;i<4;i++) {
      const int X = (i*256 + t)*16;
      const int row = X >> 8, colb = X & 255;
      gload_lds16(Kg + (size_t)(kv0+row)*4096 + (colb ^ ((row&7)<<4)), (char*)&Kl[buf][0] + X);
    }
  };
  auto stageV = [&](int buf, int kv0) {
    #pragma unroll
    for (int i=0;i<4;i++) {
      const int X = (i*256 + t)*16;
      const int row = X >> 7, colb = X & 127;
      gload_lds16(Vg + (size_t)row*2048 + kv0*2 + (colb ^ ((row&7)<<4)), (char*)&Vl[buf][0] + X);
    }
  };

  f32x4 oacc[8];
  #pragma unroll
  for (int n=0;n<8;n++) oacc[n]=zero4();
  float mrow[4], lrow[4];
  #pragma unroll
  for (int j=0;j<4;j++){ mrow[j]=-1e30f; lrow[j]=0.f; }
  const float scale = 0.08838834764831845f;

  stageK(0,0); stageV(0,0);
  __syncthreads();
  int cur = 0;

  for (int it=0; it<16; ++it) {
    const int kv0 = it*64;
    if (it < 15) { stageK(cur^1, kv0+64); stageV(cur^1, kv0+64); }

    f32x4 sc[4];
    #pragma unroll
    for (int c=0;c<4;c++) sc[c]=zero4();
    __builtin_amdgcn_s_setprio(1);
    #pragma unroll
    for (int c=0;c<4;c++) {
      const int krow = c*16+lc;
      const char* kp = (const char*)&Kl[cur][0] + krow*256;
      #pragma unroll
      for (int kk=0;kk<4;kk++) {
        bf16x8 kf = *reinterpret_cast<const bf16x8*>(kp + ((kk*64 + l4*16) ^ ((krow&7)<<4)));
        sc[c] = __builtin_amdgcn_mfma_f32_16x16x32_bf16(qf[kk], kf, sc[c], 0,0,0);
      }
    }
    __builtin_amdgcn_s_setprio(0);

    float alpha[4];
    #pragma unroll
    for (int j=0;j<4;j++) {
      float v0=sc[0][j]*scale, v1=sc[1][j]*scale, v2=sc[2][j]*scale, v3=sc[3][j]*scale;
      float mx = fmaxf(fmaxf(v0,v1),fmaxf(v2,v3));
      #pragma unroll
      for (int d=1;d<16;d<<=1) mx = fmaxf(mx, __shfl_xor(mx,d));
      float mn = fmaxf(mrow[j], mx);
      alpha[j] = __expf(mrow[j]-mn);
      mrow[j] = mn;
      float p0=__expf(v0-mn), p1=__expf(v1-mn), p2=__expf(v2-mn), p3=__expf(v3-mn);
      sc[0][j]=p0; sc[1][j]=p1; sc[2][j]=p2; sc[3][j]=p3;
      float ps = (p0+p1)+(p2+p3);
      #pragma unroll
      for (int d=1;d<16;d<<=1) ps += __shfl_xor(ps,d);
      lrow[j] = lrow[j]*alpha[j] + ps;
    }
    #pragma unroll
    for (int n=0;n<8;n++)
      #pragma unroll
      for (int j=0;j<4;j++) oacc[n][j]*=alpha[j];

    char* pw = (char*)&plds[w][0];
    #pragma unroll
    for (int c=0;c<4;c++)
      #pragma unroll
      for (int j=0;j<4;j++) {
        const int qrow = l4*4+j;
        *reinterpret_cast<bf16*>(pw + qrow*128 + ((c*32 + lc*2) ^ ((qrow&7)<<4))) =
            __float2bfloat16(sc[c][j]);
      }
    bf16x8 pf[2];
    #pragma unroll
    for (int ks=0;ks<2;ks++)
      pf[ks] = *reinterpret_cast<const bf16x8*>(pw + lc*128 + ((ks*64 + l4*16) ^ ((lc&7)<<4)));

    __builtin_amdgcn_s_setprio(1);
    #pragma unroll
    for (int n=0;n<8;n++) {
      const int drow = n*16+lc;
      const char* vp = (const char*)&Vl[cur][0] + drow*128;
      #pragma unroll
      for (int ks=0;ks<2;ks++) {
        bf16x8 vf = *reinterpret_cast<const bf16x8*>(vp + ((ks*64 + l4*16) ^ ((drow&7)<<4)));
        oacc[n] = __builtin_amdgcn_mfma_f32_16x16x32_bf16(pf[ks], vf, oacc[n], 0,0,0);
      }
    }
    __builtin_amdgcn_s_setprio(0);

    __syncthreads();
    cur ^= 1;
  }

  #pragma unroll
  for (int n=0;n<8;n++)
    #pragma unroll
    for (int j=0;j<4;j++) {
      float v = oacc[n][j]/lrow[j];
      O[((size_t)(b*1024 + q0 + l4*4 + j))*2048 + h*128 + n*16 + lc] = __float2bfloat16(v);
    }
}

// ---------------- LayerNorm (vectorized): over 2048 cols of (in0 [+in1] [+in2] [+addv(b)]) ----
__global__ __launch_bounds__(256) void k_ln(const float* __restrict__ in0, const float* __restrict__ in1,
                                            const float* __restrict__ in2, const float* __restrict__ addv,
                                            float* __restrict__ outsum,
                                            float* __restrict__ outf, bf16* __restrict__ outb,
                                            const float* __restrict__ g, const float* __restrict__ bta)
{
  const int row = blockIdx.x;
  const int b = row >> 10;
  const size_t base = (size_t)row*2048;
  const int c0 = threadIdx.x * 8;
  f32x4 v0 = *(const f32x4*)(in0 + base + c0);
  f32x4 v1 = *(const f32x4*)(in0 + base + c0 + 4);
  if (in1) { v0 += *(const f32x4*)(in1 + base + c0); v1 += *(const f32x4*)(in1 + base + c0 + 4); }
  if (in2) { v0 += *(const f32x4*)(in2 + base + c0); v1 += *(const f32x4*)(in2 + base + c0 + 4); }
  if (addv){ v0 += *(const f32x4*)(addv + b*2048 + c0); v1 += *(const f32x4*)(addv + b*2048 + c0 + 4); }
  if (outsum) { *(f32x4*)(outsum + base + c0) = v0; *(f32x4*)(outsum + base + c0 + 4) = v1; }
  float s = (v0[0]+v0[1])+(v0[2]+v0[3]) + (v1[0]+v1[1])+(v1[2]+v1[3]);
  __shared__ float red[256];
  red[threadIdx.x]=s; __syncthreads();
  for (int o=128;o>0;o>>=1){ if(threadIdx.x<o) red[threadIdx.x]+=red[threadIdx.x+o]; __syncthreads(); }
  float mean = red[0] * (1.f/2048.f);
  __syncthreads();
  float vs=0.f;
  #pragma unroll
  for (int i=0;i<4;i++){ float d=v0[i]-mean; vs+=d*d; }
  #pragma unroll
  for (int i=0;i<4;i++){ float d=v1[i]-mean; vs+=d*d; }
  red[threadIdx.x]=vs; __syncthreads();
  for (int o=128;o>0;o>>=1){ if(threadIdx.x<o) red[threadIdx.x]+=red[threadIdx.x+o]; __syncthreads(); }
  float inv = rsqrtf(red[0]*(1.f/2048.f) + 1e-5f);
  f32x4 g0 = *(const f32x4*)(g + c0),  g1v = *(const f32x4*)(g + c0 + 4);
  f32x4 b0 = *(const f32x4*)(bta + c0), b1v = *(const f32x4*)(bta + c0 + 4);
  f32x4 r0, r1;
  #pragma unroll
  for (int i=0;i<4;i++) r0[i] = (v0[i]-mean)*inv*g0[i] + b0[i];
  #pragma unroll
  for (int i=0;i<4;i++) r1[i] = (v1[i]-mean)*inv*g1v[i] + b1v[i];
  if (outf) { *(f32x4*)(outf + base + c0) = r0; *(f32x4*)(outf + base + c0 + 4) = r1; }
  if (outb) {
    union { ushort u[8]; uint4 v; } ob;
    #pragma unroll
    for (int i=0;i<4;i++) { ob.u[i] = __bfloat16_as_ushort(__float2bfloat16(r0[i]));
                            ob.u[4+i] = __bfloat16_as_ushort(__float2bfloat16(r1[i])); }
    *reinterpret_cast<uint4*>(outb + base + c0) = ob.v;
  }
}

// ---------------- pool: two-stage, vectorized ----------------
__global__ __launch_bounds__(256) void k_poolp(const float* __restrict__ in0, const float* __restrict__ in1,
                                               const float* __restrict__ in2, float* __restrict__ part) {
  const int ch = blockIdx.x, b = blockIdx.y;
  const int t = threadIdx.x;
  f32x4 a0 = zero4(), a1 = zero4();
  #pragma unroll 4
  for (int r=0;r<16;++r) {
    const size_t base = ((size_t)(b*1024 + ch*16 + r))*2048;
    a0 += *(const f32x4*)(in0 + base + t*4);
    a1 += *(const f32x4*)(in0 + base + 1024 + t*4);
    if (in1) { a0 += *(const f32x4*)(in1 + base + t*4); a1 += *(const f32x4*)(in1 + base + 1024 + t*4); }
    if (in2) { a0 += *(const f32x4*)(in2 + base + t*4); a1 += *(const f32x4*)(in2 + base + 1024 + t*4); }
  }
  float* pp = part + ((size_t)(ch*4 + b))*2048;
  *(f32x4*)(pp + t*4) = a0;
  *(f32x4*)(pp + 1024 + t*4) = a1;
}

__global__ __launch_bounds__(256) void k_pools(const float* __restrict__ part, float* __restrict__ out) {
  const int b = blockIdx.y;
  const int c = blockIdx.x*1024 + threadIdx.x*4;
  f32x4 s = zero4();
  #pragma unroll 8
  for (int ch=0;ch<64;++ch)
    s += *(const f32x4*)(part + ((size_t)(ch*4+b))*2048 + c);
  #pragma unroll
  for (int i=0;i<4;i++) s[i] *= (1.f/1024.f);
  *(f32x4*)(out + b*2048 + c) = s;
}

// ---------------- generic two-stage GEMV ----------------
// partials: P[(c*B + b)*N + n] = sum_{k in chunk c} x[b*K+k] * W[k*N+n]   (W is KxN)
template<int C>
__global__ __launch_bounds__(256) void k_gvp(const float* __restrict__ x, const float* __restrict__ W,
                                             int N, int K, float* __restrict__ P) {
  const int n = blockIdx.x*256 + threadIdx.x;
  const int b = blockIdx.y, c = blockIdx.z, B = gridDim.y;
  if (n >= N) return;
  const int kc = K / C;
  const float* xr = x + (size_t)b*K + c*kc;
  const float* Wr = W + (size_t)c*kc*N + n;
  float s = 0.f;
  #pragma unroll 4
  for (int k=0;k<kc;k++) s += xr[k]*Wr[(size_t)k*N];
  P[((size_t)(c*B + b))*N + n] = s;
}

// row-major W variant: W is NxK (each output row n dots a contiguous W row)
template<int C>
__global__ __launch_bounds__(256) void k_gvpr(const float* __restrict__ x, const float* __restrict__ W,
                                              int N, int K, float* __restrict__ P) {
  const int n = blockIdx.x*256 + threadIdx.x;
  const int b = blockIdx.y, c = blockIdx.z, B = gridDim.y;
  if (n >= N) return;
  const int kc = K / C;
  const float* xr = x + (size_t)b*K + c*kc;
  const float* Wr = W + (size_t)n*K + c*kc;
  float s = 0.f;
  #pragma unroll 4
  for (int k=0;k<kc;k++) s += xr[k]*Wr[k];
  P[((size_t)(c*B + b))*N + n] = s;
}

// combine: ACT 0: out = s*scale + bias?; 1: gelu(s+bias); 2: s+bias+aux1[b][n];
// 3: gate: sigmoid(s+bias)*0.1*aux1[b][n]/(0.1+9.9*sigmoid(aux2[n]))
template<int ACT, int C>
__global__ __launch_bounds__(256) void k_gvc(const float* __restrict__ P, int N,
                                             const float* __restrict__ bias,
                                             const float* __restrict__ aux1,
                                             const float* __restrict__ aux2,
                                             float scale, float* __restrict__ out) {
  const int n = blockIdx.x*256 + threadIdx.x;
  const int b = blockIdx.y, B = gridDim.y;
  if (n >= N) return;
  float s = 0.f;
  #pragma unroll
  for (int c=0;c<C;c++) s += P[((size_t)(c*B + b))*N + n];
  float r;
  if (ACT==0)      r = s*scale + (bias ? bias[n] : 0.f);
  else if (ACT==1) r = gelu_f(s + bias[n]);
  else if (ACT==2) r = s + bias[n] + aux1[(size_t)b*N + n];
  else {
    float gg = 1.f/(1.f+__expf(-(s + bias[n])));
    float tf = 0.1f + 9.9f/(1.f+__expf(-aux2[n]));
    r = 0.1f*gg*aux1[(size_t)b*N + n]/tf;
  }
  out[(size_t)b*N + n] = r;
}

// ---------------- remaining head kernels ----------------
__global__ __launch_bounds__(256) void k_msoftmax(float* __restrict__ mattn) {
  int b = blockIdx.x;
  __shared__ float red[256];
  float mx=-1e30f;
  for (int i=threadIdx.x;i<10000;i+=256) mx=fmaxf(mx, mattn[b*10000+i]);
  red[threadIdx.x]=mx; __syncthreads();
  for (int o=128;o>0;o>>=1){ if(threadIdx.x<o) red[threadIdx.x]=fmaxf(red[threadIdx.x],red[threadIdx.x+o]); __syncthreads(); }
  mx=red[0]; __syncthreads();
  float sm=0.f;
  for (int i=threadIdx.x;i<10000;i+=256){ float e=__expf(mattn[b*10000+i]-mx); mattn[b*10000+i]=e; sm+=e; }
  red[threadIdx.x]=sm; __syncthreads();
  for (int o=128;o>0;o>>=1){ if(threadIdx.x<o) red[threadIdx.x]+=red[threadIdx.x+o]; __syncthreads(); }
  float inv = 1.f/red[0];
  for (int i=threadIdx.x;i<10000;i+=256) mattn[b*10000+i]*=inv;
}

__global__ void k_out(const float* __restrict__ a1, const float* __restrict__ w_a2, const float* __restrict__ b_a2,
                      const float* __restrict__ v1, const float* __restrict__ w_v2, const float* __restrict__ b_v2,
                      float* __restrict__ out) {
  int idx = blockIdx.x*256 + threadIdx.x;  // 1024
  if (idx < 1024) {
    int b = idx>>8, n = idx&255;
    float s = b_a2[n];
    for (int k=0;k<1024;k++) s += a1[b*1024+k]*w_a2[(size_t)k*256+n];
    out[b*256+n]=s;
  }
  if (idx < 4) {
    float s = b_v2[0];
    for (int k=0;k<1024;k++) s += v1[idx*1024+k]*w_v2[k];
    out[1024+idx]=s;
  }
}

extern "C" void kernel_launch(void* const* d_in, const int* in_sizes, int n_in,
                              void* d_out, int out_size, void* d_ws, size_t ws_size,
                              hipStream_t stream)
{
  (void)in_sizes; (void)n_in; (void)out_size;
  const float* x     = (const float*)d_in[0];
  const float* w_in  = (const float*)d_in[1];
  const float* b_in  = (const float*)d_in[2];
  const float* g_in  = (const float*)d_in[3];
  const float* be_in = (const float*)d_in[4];
  const float* wq    = (const float*)d_in[5];
  const float* wk    = (const float*)d_in[6];
  const float* wv    = (const float*)d_in[7];
  const float* wo    = (const float*)d_in[8];
  const float* g1    = (const float*)d_in[11];
  const float* be1   = (const float*)d_in[12];
  const float* g2    = (const float*)d_in[13];
  const float* be2   = (const float*)d_in[14];
  const float* wff1  = (const float*)d_in[15];
  const float* bff1  = (const float*)d_in[16];
  const float* wff2  = (const float*)d_in[17];
  const float* bff2  = (const float*)d_in[18];
  const float* wgate = (const float*)d_in[19];
  const float* bgate = (const float*)d_in[20];
  const float* tauff = (const float*)d_in[21];
  const float* bank  = (const float*)d_in[22];
  const float* w_mp  = (const float*)d_in[23];
  const float* b_mp  = (const float*)d_in[24];
  const float* w_mr  = (const float*)d_in[25];
  const float* b_mr  = (const float*)d_in[26];
  const float* w_a1  = (const float*)d_in[27];
  const float* b_a1  = (const float*)d_in[28];
  const float* w_a2  = (const float*)d_in[29];
  const float* b_a2  = (const float*)d_in[30];
  const float* w_v1  = (const float*)d_in[31];
  const float* b_v1  = (const float*)d_in[32];
  const float* w_v2  = (const float*)d_in[33];
  const float* b_v2  = (const float*)d_in[34];
  float* out = (float*)d_out;

  char* ws = (char*)d_ws;
  size_t o = 0;
  auto alloc = [&](size_t bytes)->char* { char* p = ws + o; o += (bytes + 255) & ~(size_t)255; return p; };
  bf16*  WINT   = (bf16*) alloc(2048ull*1024*2);
  bf16*  WT     = (bf16*) alloc(33554432ull);
  float* XF     = (float*)alloc(33554432ull);
  bf16*  XBF    = (bf16*) alloc(16777216ull);
  float* COS    = (float*)alloc(262144);
  float* SIN    = (float*)alloc(262144);
  float* XP     = (float*)alloc(32768);
  float* HF     = (float*)alloc(32768);
  float* POOLED = (float*)alloc(32768);
  float* QM     = (float*)alloc(8192);
  float* MATTN  = (float*)alloc(160000);
  float* MIDS   = (float*)alloc(8192);
  float* FEAT   = (float*)alloc(32768);
  float* A1     = (float*)alloc(16384);
  float* V1     = (float*)alloc(16384);
  float* PPART  = (float*)alloc(2097152);
  float* GP     = (float*)alloc(2621440);       // GEMV partials (max 4*4*10000*4B = 640KB; headroom)
  bf16*  BUF    = (bf16*) alloc(5ull*16777216);
  float* P0     = (float*)alloc(33554432ull);   // split-K partial 0 (4096x2048 fp32)
  float* P1     = (float*)alloc(33554432ull);   // split-K partial 1
  if (o > ws_size) return;

  const size_t EB = 8388608;
  bf16* QKV = BUF + 0*EB;          // fused q|k|v output, 4096 x 6144, spans BUF0..BUF2
  bf16* QR  = BUF + 3*EB;
  bf16* KR  = BUF + 4*EB;
  bf16* VT  = (bf16*)WT;           // into dead WTq/WTk (after QKV gemm)
  bf16* AO  = BUF + 0*EB;          // reuses QKV after ropes/vtrans
  bf16* MID = BUF + 0*EB;          // ff1 out, spans BUF0..BUF3
  bf16* XINB = BUF + 0*EB;

  bf16* WTq = WT;            bf16* WTk = WT + 4194304;
  bf16* WTv = WT + 8388608;  bf16* WTo = WT + 12582912;

  // ---- prologue ----
  k_cossin<<<256, 256, 0, stream>>>(COS, SIN);
  k_cvt<<<4096, 256, 0, stream>>>(x, XINB, 1048576);
  k_tr64<<<dim3(32,16), 256, 0, stream>>>(w_in, WINT, 1024, 2048);
  k_gemm2<5,4><<<dim3(8,16,2), 512, 0, stream>>>(XINB, WINT, 4096, 2048, 512, 1024, P0, (bf16*)nullptr, b_in);
  k_ln<<<4096, 256, 0, stream>>>(P0, P1, (const float*)nullptr, (const float*)nullptr,
                                 (float*)nullptr, XF, XBF, g_in, be_in);

  for (int i=0;i<2;i++) {
    const size_t ws2 = (size_t)i*2048*2048;
    k_tr64<<<dim3(32,32), 256, 0, stream>>>(wq + ws2, WTq, 2048, 2048);
    k_tr64<<<dim3(32,32), 256, 0, stream>>>(wk + ws2, WTk, 2048, 2048);
    k_tr64<<<dim3(32,32), 256, 0, stream>>>(wv + ws2, WTv, 2048, 2048);
    k_tr64<<<dim3(32,32), 256, 0, stream>>>(wo + ws2, WTo, 2048, 2048);
    // fused QKV projection: N=6144
    k_gemm2<1,6><<<dim3(24,16), 512, 0, stream>>>(XBF, WTq, 4096, 6144, 2048, 2048, (float*)nullptr, QKV, (const float*)nullptr);
    // RoPE + V transpose (VT lives in dead WTq/WTk region)
    k_rope<<<8192, 256, 0, stream>>>(QKV,        6144, QR, COS, SIN);
    k_rope<<<8192, 256, 0, stream>>>(QKV + 2048, 6144, KR, COS, SIN);
    k_vtrans<<<dim3(64,32,4), 256, 0, stream>>>(QKV + 4096, 6144, VT);
    // attention
    k_attn<<<dim3(64,16), 256, 0, stream>>>(QR, KR, VT, AO);
    // output proj, split-K=2 -> P0,P1 ; ln combines x1 = XF+P0+P1, writes back + bf16
    k_gemm2<6,4><<<dim3(8,16,2), 512, 0, stream>>>(AO, WTo, 4096, 2048, 1024, 2048, P0, (bf16*)nullptr, (const float*)nullptr);
    k_ln<<<4096, 256, 0, stream>>>(XF, P0, P1, (const float*)nullptr,
                                   XF, (float*)nullptr, XBF, g1 + i*2048, be1 + i*2048);
    // FFN
    k_tr64<<<dim3(128,32), 256, 0, stream>>>(wff1 + (size_t)i*2048*8192, WT, 2048, 8192);
    k_gemm2<3,8><<<dim3(32,16), 512, 0, stream>>>(XBF, WT, 4096, 8192, 2048, 2048, (float*)nullptr, MID, bff1 + i*8192);
    k_tr64<<<dim3(32,128), 256, 0, stream>>>(wff2 + (size_t)i*8192*2048, WT, 8192, 2048);
    // ff2, split-K=2 (K=8192 -> 2x4096) -> P0 (with bias), P1
    k_gemm2<5,4><<<dim3(8,16,2), 512, 0, stream>>>(MID, WT, 4096, 2048, 4096, 8192, P0, (bf16*)nullptr, bff2 + i*2048);
    // liquid gate + final LN (x2 = XF + P0 + P1)
    k_poolp<<<dim3(64,4), 256, 0, stream>>>(XF, P0, P1, PPART);
    k_pools<<<dim3(2,4), 256, 0, stream>>>(PPART, XP);
    k_gvp<8><<<dim3(8,4,8), 256, 0, stream>>>(XP, wgate + ws2, 2048, 2048, GP);
    k_gvc<3,8><<<dim3(8,4), 256, 0, stream>>>(GP, 2048, bgate + i*2048, XP, tauff + i*2048, 1.f, HF);
    k_ln<<<4096, 256, 0, stream>>>(XF, P0, P1, HF,
                                   (float*)nullptr, XF, XBF, g2 + i*2048, be2 + i*2048);
  }

  // ---- head ----
  k_poolp<<<dim3(64,4), 256, 0, stream>>>(XF, (const float*)nullptr, (const float*)nullptr, PPART);
  k_pools<<<dim3(2,4), 256, 0, stream>>>(PPART, POOLED);
  // qm = pooled @ w_mp + b_mp
  k_gvp<8><<<dim3(2,4,8), 256, 0, stream>>>(POOLED, w_mp, 512, 2048, GP);
  k_gvc<0,8><<<dim3(2,4), 256, 0, stream>>>(GP, 512, b_mp, (const float*)nullptr, (const float*)nullptr, 1.f, QM);
  // mattn = qm @ bank^T * sc  (bank is NxK row-major)
  k_gvpr<4><<<dim3(40,4,4), 256, 0, stream>>>(QM, bank, 10000, 512, GP);
  k_gvc<0,4><<<dim3(40,4), 256, 0, stream>>>(GP, 10000, (const float*)nullptr, (const float*)nullptr,
                                             (const float*)nullptr, 0.04419417382415922f, MATTN);
  k_msoftmax<<<4, 256, 0, stream>>>(MATTN);
  // mid = mattn @ bank  (bank as KxN with K=10000, N=512)
  k_gvp<16><<<dim3(2,4,16), 256, 0, stream>>>(MATTN, bank, 512, 10000, GP);
  k_gvc<0,16><<<dim3(2,4), 256, 0, stream>>>(GP, 512, (const float*)nullptr, (const float*)nullptr,
                                             (const float*)nullptr, 1.f, MIDS);
  // feat = mid @ w_mr + b_mr + pooled
  k_gvp<4><<<dim3(8,4,4), 256, 0, stream>>>(MIDS, w_mr, 2048, 512, GP);
  k_gvc<2,4><<<dim3(8,4), 256, 0, stream>>>(GP, 2048, b_mr, POOLED, (const float*)nullptr, 1.f, FEAT);
  // a1 = gelu(feat @ w_a1 + b_a1) ; v1 = gelu(feat @ w_v1 + b_v1)
  k_gvp<8><<<dim3(4,4,8), 256, 0, stream>>>(FEAT, w_a1, 1024, 2048, GP);
  k_gvc<1,8><<<dim3(4,4), 256, 0, stream>>>(GP, 1024, b_a1, (const float*)nullptr, (const float*)nullptr, 1.f, A1);
  k_gvp<8><<<dim3(4,4,8), 256, 0, stream>>>(FEAT, w_v1, 1024, 2048, GP);
  k_gvc<1,8><<<dim3(4,4), 256, 0, stream>>>(GP, 1024, b_v1, (const float*)nullptr, (const float*)nullptr, 1.f, V1);
  k_out<<<4, 256, 0, stream>>>(A1, w_a2, b_a2, V1, w_v2, b_v2, out);
}